// Round 13
// baseline (750.513 us; speedup 1.0000x reference)
//
#include <hip/hip_runtime.h>
#include <hip/hip_fp16.h>
#include <math.h>

#define N_NODES 100000
#define N_EDGES 1600000
#define N_GRAPHS 2048
#define NCLS 204
#define EPS_BN 1e-5f
#define NBUCK ((N_NODES + 255) / 256)   // 391
#define BIN_CHUNK 8192

typedef __attribute__((ext_vector_type(8))) _Float16 f16x8;
typedef __attribute__((ext_vector_type(4))) float f32x4;

__device__ __forceinline__ uint pack2h(float a, float b) {
  __half2 h = __floats2half2_rn(a, b);
  return *reinterpret_cast<uint*>(&h);
}
__device__ __forceinline__ float2 unpack2h(uint u) {
  __half2 h = *reinterpret_cast<__half2*>(&u);
  return __half22float2(h);
}
__device__ __forceinline__ ushort f2h(float v) {
  __half h = __float2half_rn(v);
  return *reinterpret_cast<ushort*>(&h);
}

// ---------------- CSR build (binned; csr holds BYTE offsets src*256) ----------------
__global__ __launch_bounds__(256) void k_bin_count(const int* __restrict__ dst,
                                                   int* __restrict__ bcnt, int E) {
  __shared__ int hist[NBUCK];
  int t = threadIdx.x;
  int e0 = blockIdx.x * BIN_CHUNK;
  for (int b = t; b < NBUCK; b += 256) hist[b] = 0;
  __syncthreads();
  for (int e = e0 + t; e < min(e0 + BIN_CHUNK, E); e += 256)
    atomicAdd(&hist[dst[e] >> 8], 1);
  __syncthreads();
  for (int b = t; b < NBUCK; b += 256)
    if (hist[b] > 0) atomicAdd(&bcnt[b], hist[b]);
}

__global__ __launch_bounds__(512) void k_bucket_scan(const int* __restrict__ bcnt,
                                                     int* __restrict__ bbase,
                                                     int* __restrict__ bcur) {
  __shared__ int sh[512];
  int t = threadIdx.x;
  int v = (t < NBUCK) ? bcnt[t] : 0;
  sh[t] = v;
  __syncthreads();
  for (int d = 1; d < 512; d <<= 1) {
    int x = (t >= d) ? sh[t - d] : 0;
    __syncthreads();
    sh[t] += x;
    __syncthreads();
  }
  if (t < NBUCK) {
    bbase[t + 1] = sh[t];
    bcur[t] = sh[t] - v;
    if (t == 0) bbase[0] = 0;
  }
}

__global__ __launch_bounds__(256) void k_bin(const int* __restrict__ src,
                                             const int* __restrict__ dst,
                                             int* __restrict__ cursor,
                                             uint* __restrict__ staging, int E) {
  __shared__ int hist[NBUCK];
  __shared__ int base_s[NBUCK];
  int t = threadIdx.x;
  int e0 = blockIdx.x * BIN_CHUNK;
  for (int b = t; b < NBUCK; b += 256) hist[b] = 0;
  __syncthreads();
  for (int e = e0 + t; e < min(e0 + BIN_CHUNK, E); e += 256)
    atomicAdd(&hist[dst[e] >> 8], 1);
  __syncthreads();
  for (int b = t; b < NBUCK; b += 256) {
    int hh = hist[b];
    if (hh > 0) base_s[b] = atomicAdd(&cursor[b], hh);
    hist[b] = 0;
  }
  __syncthreads();
  for (int e = e0 + t; e < min(e0 + BIN_CHUNK, E); e += 256) {
    int d = dst[e];
    int b = d >> 8;
    int r = atomicAdd(&hist[b], 1);
    staging[base_s[b] + r] = (uint)src[e] | ((uint)(d & 255) << 24);
  }
}

__global__ __launch_bounds__(256) void k_place2(const uint* __restrict__ staging,
                                                const int* __restrict__ bbase,
                                                int* __restrict__ row_ptr,
                                                uint* __restrict__ csrb, int nNodes, int E) {
  __shared__ int cnt[256];
  __shared__ int scn[256];
  __shared__ int cur[256];
  int t = threadIdx.x;
  int b = blockIdx.x;
  int n0 = b * 256;
  cnt[t] = 0;
  __syncthreads();
  int s = bbase[b], e = bbase[b + 1];
  for (int i = s + t; i < e; i += 256) atomicAdd(&cnt[staging[i] >> 24], 1);
  __syncthreads();
  int v = cnt[t];
  scn[t] = v;
  __syncthreads();
  for (int d = 1; d < 256; d <<= 1) {
    int x = (t >= d) ? scn[t - d] : 0;
    __syncthreads();
    scn[t] += x;
    __syncthreads();
  }
  int excl = scn[t] - v;
  if (n0 + t < nNodes) row_ptr[n0 + t] = s + excl;
  cur[t] = s + excl;
  __syncthreads();
  for (int i = s + t; i < e; i += 256) {
    uint ed = staging[i];
    int pos = atomicAdd(&cur[ed >> 24], 1);
    csrb[pos] = (ed & 0xFFFFFF) << 8;   // byte offset of src row (256B rows)
  }
  if (b == 0 && t == 0) row_ptr[nNodes] = E;
}

// ---------------- conversions / weight prep (fp16) ----------------
__global__ void k_conv_h(const float* __restrict__ h, uint* __restrict__ hb, int nNodes) {
  int i = blockIdx.x * blockDim.x + threadIdx.x;
  if (i < nNodes * 64) {
    int n = i >> 6, cp = i & 63;
    int c = cp * 2;
    float a = (c < 78) ? h[(size_t)n * 78 + c] : 0.0f;
    float b = (c + 1 < 78) ? h[(size_t)n * 78 + c + 1] : 0.0f;
    hb[i] = pack2h(a, b);
  }
}

__global__ void k_prep_wt_all(const float* __restrict__ W1, const float* __restrict__ Wg,
                              ushort* __restrict__ Wt) {
  int i = blockIdx.x * blockDim.x + threadIdx.x;
  int layer = blockIdx.y;
  if (i < 128 * 128) {
    int n = i >> 7, k = i & 127;
    const float* W = (layer == 0) ? W1 : Wg + (size_t)(layer - 1) * 128 * 128;
    int K = (layer == 0) ? 78 : 128;
    float v = (k < K) ? W[(size_t)k * 128 + n] : 0.0f;
    Wt[(size_t)layer * 128 * 128 + i] = f2h(v);
  }
}

__global__ void k_prep_wt_gen(const float* __restrict__ W, int wld, int col_off, int nkeep,
                              int K, ushort* __restrict__ Wt, int total) {
  int i = blockIdx.x * blockDim.x + threadIdx.x;
  if (i < total) {
    int n = i / K, k = i - n * K;
    float v = (n < nkeep) ? W[(size_t)k * wld + col_off + n] : 0.0f;
    Wt[i] = f2h(v);
  }
}

__global__ void k_bnparams(const float* __restrict__ sum, const float* __restrict__ sumsq,
                           const float* __restrict__ gamma, const float* __restrict__ beta,
                           float* __restrict__ Ac, float* __restrict__ Bc,
                           int C, float invM) {
  int c = blockIdx.x * blockDim.x + threadIdx.x;
  if (c < C) {
    float mu = sum[c] * invM;
    float var = sumsq[c] * invM - mu * mu;
    float rs = rsqrtf(var + EPS_BN);
    float a = gamma[c] * rs;
    Ac[c] = a;
    Bc[c] = beta[c] - mu * a;
  }
}

// ---------------- activation: xact = relu(y*A+B), params computed per-block in LDS ----------------
__global__ __launch_bounds__(256) void k_act(const uint4* __restrict__ y4,
                                             const float* __restrict__ psum,
                                             const float* __restrict__ psq,
                                             const float* __restrict__ pgamma,
                                             const float* __restrict__ pbeta,
                                             float invM,
                                             uint4* __restrict__ x4, int total4) {
  __shared__ float As[128], Bs[128];
  int t = threadIdx.x;
  if (t < 128) {
    float mu = psum[t] * invM;
    float var = psq[t] * invM - mu * mu;
    float a = pgamma[t] * rsqrtf(var + EPS_BN);
    As[t] = a;
    Bs[t] = pbeta[t] - mu * a;
  }
  __syncthreads();
  int i = blockIdx.x * blockDim.x + t;
  if (i < total4) {
    int c = ((i * 4) & 63) * 2;
    float4 A0 = *reinterpret_cast<const float4*>(As + c);
    float4 A1 = *reinterpret_cast<const float4*>(As + c + 4);
    float4 B0 = *reinterpret_cast<const float4*>(Bs + c);
    float4 B1 = *reinterpret_cast<const float4*>(Bs + c + 4);
    uint4 v = y4[i];
    float2 f0 = unpack2h(v.x), f1 = unpack2h(v.y), f2 = unpack2h(v.z), f3 = unpack2h(v.w);
    uint4 o;
    o.x = pack2h(fmaxf(f0.x * A0.x + B0.x, 0.f), fmaxf(f0.y * A0.y + B0.y, 0.f));
    o.y = pack2h(fmaxf(f1.x * A0.z + B0.z, 0.f), fmaxf(f1.y * A0.w + B0.w, 0.f));
    o.z = pack2h(fmaxf(f2.x * A1.x + B1.x, 0.f), fmaxf(f2.y * A1.y + B1.y, 0.f));
    o.w = pack2h(fmaxf(f3.x * A1.z + B1.z, 0.f), fmaxf(f3.y * A1.w + B1.w, 0.f));
    x4[i] = o;
  }
}

// ---------------- GIN aggregation: pure sum, 4-slot dwordx4 gather, 4-deep MLP ----------------
// NOTE: every __shfl executed by ALL lanes (uniform exec) — shfl from an
// exec-masked-off source lane returns 0 on CDNA (round-9 bug).
__global__ __launch_bounds__(256) void k_agg(const char* __restrict__ xraw,
                                             const int* __restrict__ row_ptr,
                                             const uint* __restrict__ csrb,
                                             char* __restrict__ Mraw, int nNodes) {
  int n = blockIdx.x * 4 + (threadIdx.x >> 6);
  if (n >= nNodes) return;
  int l = threadIdx.x & 63;
  int slot = l >> 4;
  int coff = (l & 15) * 16;

  float acc[8];
#pragma unroll
  for (int k = 0; k < 8; k++) acc[k] = 0.f;

  auto accum = [&](uint4 v) {
    float2 f0 = unpack2h(v.x), f1 = unpack2h(v.y), f2 = unpack2h(v.z), f3 = unpack2h(v.w);
    acc[0] += f0.x; acc[1] += f0.y;
    acc[2] += f1.x; acc[3] += f1.y;
    acc[4] += f2.x; acc[5] += f2.y;
    acc[6] += f3.x; acc[7] += f3.y;
  };

  if (slot == 0) {
    uint4 v = *reinterpret_cast<const uint4*>(xraw + (size_t)n * 256 + coff);
    float2 f0 = unpack2h(v.x), f1 = unpack2h(v.y), f2 = unpack2h(v.z), f3 = unpack2h(v.w);
    acc[0] = 2.f * f0.x; acc[1] = 2.f * f0.y;
    acc[2] = 2.f * f1.x; acc[3] = 2.f * f1.y;
    acc[4] = 2.f * f2.x; acc[5] = 2.f * f2.y;
    acc[6] = 2.f * f3.x; acc[7] = 2.f * f3.y;
  }

  int s = row_ptr[n], e = row_ptr[n + 1];
  for (int base = s; base < e; base += 64) {
    int cnt = e - base;
    if (cnt > 64) cnt = 64;
    uint myoff = (base + l < e) ? csrb[base + l] : 0;
    int nfull = cnt >> 2;
    int j = 0;
    for (; j + 4 <= nfull; j += 4) {
      uint o0 = __shfl(myoff, 4 * j + slot);
      uint o1 = __shfl(myoff, 4 * (j + 1) + slot);
      uint o2 = __shfl(myoff, 4 * (j + 2) + slot);
      uint o3 = __shfl(myoff, 4 * (j + 3) + slot);
      uint4 v0 = *reinterpret_cast<const uint4*>(xraw + (size_t)o0 + coff);
      uint4 v1 = *reinterpret_cast<const uint4*>(xraw + (size_t)o1 + coff);
      uint4 v2 = *reinterpret_cast<const uint4*>(xraw + (size_t)o2 + coff);
      uint4 v3 = *reinterpret_cast<const uint4*>(xraw + (size_t)o3 + coff);
      accum(v0); accum(v1); accum(v2); accum(v3);
    }
    for (; j < nfull; j++) {
      uint off = __shfl(myoff, 4 * j + slot);
      uint4 v = *reinterpret_cast<const uint4*>(xraw + (size_t)off + coff);
      accum(v);
    }
    int jj = nfull * 4 + slot;
    uint off = __shfl(myoff, jj < 64 ? jj : 63);
    if (jj < cnt) {
      uint4 v = *reinterpret_cast<const uint4*>(xraw + (size_t)off + coff);
      accum(v);
    }
  }

#pragma unroll
  for (int k = 0; k < 8; k++) {
    acc[k] += __shfl_xor(acc[k], 16);
    acc[k] += __shfl_xor(acc[k], 32);
  }
  if (slot == 0) {
    uint4 o;
    o.x = pack2h(acc[0], acc[1]);
    o.y = pack2h(acc[2], acc[3]);
    o.z = pack2h(acc[4], acc[5]);
    o.w = pack2h(acc[6], acc[7]);
    *reinterpret_cast<uint4*>(Mraw + (size_t)n * 256 + coff) = o;
  }
}

// ---------------- node-layer MFMA GEMM (fp16), B read from global (L1-resident) ----------------
#define SWZ(row, boff) ((boff) ^ (((row) & 7) << 4))
__global__ __launch_bounds__(256) void k_gemm_mfma(const ushort* __restrict__ A,
                                                   const ushort* __restrict__ Wt,
                                                   const float* __restrict__ bias, float bscale,
                                                   ushort* __restrict__ Y, int Mrows,
                                                   float* __restrict__ gsum,
                                                   float* __restrict__ gsq) {
  __shared__ ushort As[128 * 128];
  __shared__ float sred[4][128], qred[4][128];
  int t = threadIdx.x;
  int r0 = blockIdx.x * 128;
  char* Ab = (char*)As;

  // stage A only (32KB LDS)
  for (int it = 0; it < 8; it++) {
    int e = it * 256 + t;
    int row = e >> 4, seg = e & 15;
    uint4 va = make_uint4(0, 0, 0, 0);
    int gr = r0 + row;
    if (gr < Mrows) va = *reinterpret_cast<const uint4*>(A + (size_t)gr * 128 + seg * 8);
    *reinterpret_cast<uint4*>(Ab + row * 256 + SWZ(row, seg * 16)) = va;
  }
  __syncthreads();

  int wi = t >> 6;
  int l = t & 63;
  int lr = l & 15;
  int kp = l >> 4;

  f32x4 acc[2][8];
#pragma unroll
  for (int mi = 0; mi < 2; mi++)
#pragma unroll
    for (int ni = 0; ni < 8; ni++) acc[mi][ni] = (f32x4){0.f, 0.f, 0.f, 0.f};

#pragma unroll
  for (int ki = 0; ki < 4; ki++) {
    f16x8 a[2], b[8];
#pragma unroll
    for (int mi = 0; mi < 2; mi++) {
      int row = wi * 32 + mi * 16 + lr;
      a[mi] = *reinterpret_cast<const f16x8*>(Ab + row * 256 + SWZ(row, ki * 64 + kp * 16));
    }
#pragma unroll
    for (int ni = 0; ni < 8; ni++) {
      int row = ni * 16 + lr;
      b[ni] = *reinterpret_cast<const f16x8*>(Wt + (size_t)row * 128 + ki * 32 + kp * 8);
    }
#pragma unroll
    for (int mi = 0; mi < 2; mi++)
#pragma unroll
      for (int ni = 0; ni < 8; ni++)
        acc[mi][ni] = __builtin_amdgcn_mfma_f32_16x16x32_f16(a[mi], b[ni], acc[mi][ni], 0, 0, 0);
  }

  float s_part[8], q_part[8];
#pragma unroll
  for (int ni = 0; ni < 8; ni++) { s_part[ni] = 0.f; q_part[ni] = 0.f; }

#pragma unroll
  for (int mi = 0; mi < 2; mi++) {
    int rbase = r0 + wi * 32 + mi * 16 + kp * 4;
#pragma unroll
    for (int ni = 0; ni < 8; ni++) {
      int col = ni * 16 + lr;
      float bb = bscale * bias[col];
#pragma unroll
      for (int j = 0; j < 4; j++) {
        int r = rbase + j;
        if (r < Mrows) {
          float yv = acc[mi][ni][j] + bb;
          Y[(size_t)r * 128 + col] = f2h(yv);
          s_part[ni] += yv;
          q_part[ni] += yv * yv;
        }
      }
    }
  }

#pragma unroll
  for (int ni = 0; ni < 8; ni++) {
    s_part[ni] += __shfl_xor(s_part[ni], 16, 64);
    s_part[ni] += __shfl_xor(s_part[ni], 32, 64);
    q_part[ni] += __shfl_xor(q_part[ni], 16, 64);
    q_part[ni] += __shfl_xor(q_part[ni], 32, 64);
  }
  if (kp == 0) {
#pragma unroll
    for (int ni = 0; ni < 8; ni++) {
      sred[wi][ni * 16 + lr] = s_part[ni];
      qred[wi][ni * 16 + lr] = q_part[ni];
    }
  }
  __syncthreads();
  if (t < 128) {
    float S = sred[0][t] + sred[1][t] + sred[2][t] + sred[3][t];
    float Q = qred[0][t] + qred[1][t] + qred[2][t] + qred[3][t];
    atomicAdd(&gsum[t], S);
    atomicAdd(&gsq[t], Q);
  }
}

// ---------------- head MFMA GEMM (fp16) ----------------
template <int AMODE, int OMODE>
__global__ __launch_bounds__(256) void k_head_mfma(const void* __restrict__ Aptr,
                                                   int Mrows, int K,
                                                   const ushort* __restrict__ Wt,
                                                   const float* __restrict__ bias,
                                                   int col_off, int ncols,
                                                   const float* __restrict__ nAc,
                                                   const float* __restrict__ nBc,
                                                   void* __restrict__ Yout, int Nld,
                                                   float* __restrict__ gsum,
                                                   float* __restrict__ gsq) {
  __shared__ ushort As[128 * 128];
  __shared__ ushort Bs[128 * 128];
  __shared__ float sred[4][128], qred[4][128];
  int t = threadIdx.x;
  int r0 = blockIdx.y * 128;
  int c0 = blockIdx.x * 128;
  char* Ab = (char*)As;
  char* Bb = (char*)Bs;

  int wi = t >> 6;
  int l = t & 63;
  int lr = l & 15;
  int kp = l >> 4;

  f32x4 acc[2][8];
#pragma unroll
  for (int mi = 0; mi < 2; mi++)
#pragma unroll
    for (int ni = 0; ni < 8; ni++) acc[mi][ni] = (f32x4){0.f, 0.f, 0.f, 0.f};

  for (int k0 = 0; k0 < K; k0 += 128) {
    if (k0) __syncthreads();
    for (int it = 0; it < 8; it++) {
      int e = it * 256 + t;
      int row = e >> 4, seg = e & 15;
      int gr = r0 + row;
      uint4 va;
      if (AMODE == 0) {
        const float* Af = (const float*)Aptr;
        float4 f0 = {0.f, 0.f, 0.f, 0.f}, f1 = {0.f, 0.f, 0.f, 0.f};
        if (gr < Mrows) {
          f0 = *reinterpret_cast<const float4*>(Af + (size_t)gr * K + k0 + seg * 8);
          f1 = *reinterpret_cast<const float4*>(Af + (size_t)gr * K + k0 + seg * 8 + 4);
        }
        va.x = pack2h(f0.x, f0.y); va.y = pack2h(f0.z, f0.w);
        va.z = pack2h(f1.x, f1.y); va.w = pack2h(f1.z, f1.w);
      } else {
        const uint* Au = (const uint*)Aptr;
        uint4 r4 = make_uint4(0, 0, 0, 0);
        if (gr < Mrows) r4 = *reinterpret_cast<const uint4*>(Au + (size_t)gr * (K >> 1) + ((k0 + seg * 8) >> 1));
        int c = k0 + seg * 8;
        uint uu[4] = {r4.x, r4.y, r4.z, r4.w};
#pragma unroll
        for (int q = 0; q < 4; q++) {
          float2 f = unpack2h(uu[q]);
          float aa = fmaxf(f.x * nAc[c + 2 * q] + nBc[c + 2 * q], 0.f);
          float bb = fmaxf(f.y * nAc[c + 2 * q + 1] + nBc[c + 2 * q + 1], 0.f);
          uu[q] = pack2h(aa, bb);
        }
        va = make_uint4(uu[0], uu[1], uu[2], uu[3]);
      }
      *reinterpret_cast<uint4*>(Ab + row * 256 + SWZ(row, seg * 16)) = va;
      uint4 vb = *reinterpret_cast<const uint4*>(Wt + (size_t)(c0 + row) * K + k0 + seg * 8);
      *reinterpret_cast<uint4*>(Bb + row * 256 + SWZ(row, seg * 16)) = vb;
    }
    __syncthreads();

#pragma unroll
    for (int ki = 0; ki < 4; ki++) {
      f16x8 a[2], b[8];
#pragma unroll
      for (int mi = 0; mi < 2; mi++) {
        int row = wi * 32 + mi * 16 + lr;
        a[mi] = *reinterpret_cast<const f16x8*>(Ab + row * 256 + SWZ(row, ki * 64 + kp * 16));
      }
#pragma unroll
      for (int ni = 0; ni < 8; ni++) {
        int row = ni * 16 + lr;
        b[ni] = *reinterpret_cast<const f16x8*>(Bb + row * 256 + SWZ(row, ki * 64 + kp * 16));
      }
#pragma unroll
      for (int mi = 0; mi < 2; mi++)
#pragma unroll
        for (int ni = 0; ni < 8; ni++)
          acc[mi][ni] = __builtin_amdgcn_mfma_f32_16x16x32_f16(a[mi], b[ni], acc[mi][ni], 0, 0, 0);
    }
  }

  if (OMODE == 0) {
    float s_part[8], q_part[8];
#pragma unroll
    for (int ni = 0; ni < 8; ni++) { s_part[ni] = 0.f; q_part[ni] = 0.f; }
#pragma unroll
    for (int mi = 0; mi < 2; mi++) {
      int rbase = r0 + wi * 32 + mi * 16 + kp * 4;
#pragma unroll
      for (int ni = 0; ni < 8; ni++) {
        int gc = c0 + ni * 16 + lr;
        float bb = bias[col_off + gc];
#pragma unroll
        for (int j = 0; j < 4; j++) {
          int r = rbase + j;
          if (r < Mrows) {
            float yv = acc[mi][ni][j] + bb;
            ((ushort*)Yout)[(size_t)r * Nld + gc] = f2h(yv);
            s_part[ni] += yv;
            q_part[ni] += yv * yv;
          }
        }
      }
    }
#pragma unroll
    for (int ni = 0; ni < 8; ni++) {
      s_part[ni] += __shfl_xor(s_part[ni], 16, 64);
      s_part[ni] += __shfl_xor(s_part[ni], 32, 64);
      q_part[ni] += __shfl_xor(q_part[ni], 16, 64);
      q_part[ni] += __shfl_xor(q_part[ni], 32, 64);
    }
    if (kp == 0) {
#pragma unroll
      for (int ni = 0; ni < 8; ni++) {
        sred[wi][ni * 16 + lr] = s_part[ni];
        qred[wi][ni * 16 + lr] = q_part[ni];
      }
    }
    __syncthreads();
    if (t < 128) {
      float S = sred[0][t] + sred[1][t] + sred[2][t] + sred[3][t];
      float Q = qred[0][t] + qred[1][t] + qred[2][t] + qred[3][t];
      atomicAdd(&gsum[c0 + t], S);
      atomicAdd(&gsq[c0 + t], Q);
    }
  } else {
#pragma unroll
    for (int mi = 0; mi < 2; mi++) {
      int rbase = r0 + wi * 32 + mi * 16 + kp * 4;
#pragma unroll
      for (int ni = 0; ni < 8; ni++) {
        int gc = c0 + ni * 16 + lr;
        if (gc < ncols) {
          float bb = bias[col_off + gc];
#pragma unroll
          for (int j = 0; j < 4; j++) {
            int r = rbase + j;
            if (r < Mrows) {
              float v = acc[mi][ni][j] + bb;
              ((float*)Yout)[(size_t)r * Nld + gc] = 1.0f / (1.0f + expf(-v));
            }
          }
        }
      }
    }
  }
}

// ---------------- graph readout (fp16 y): xg[g] = sum relu(y*A+B), inline BN params ----------------
__global__ __launch_bounds__(64) void k_readout(const uint* __restrict__ y,
                                                const int* __restrict__ gid,
                                                const float* __restrict__ psum,
                                                const float* __restrict__ psq,
                                                const float* __restrict__ pgamma,
                                                const float* __restrict__ pbeta,
                                                float invM,
                                                float* __restrict__ xg, int nNodes) {
  int l = threadIdx.x;
  int n0 = blockIdx.x * 64;
  int n1 = min(n0 + 64, nNodes);
  if (n0 >= nNodes) return;
  int c0 = 2 * l, c1 = 2 * l + 1;
  float mu0 = psum[c0] * invM;
  float va0 = psq[c0] * invM - mu0 * mu0;
  float A0 = pgamma[c0] * rsqrtf(va0 + EPS_BN);
  float B0 = pbeta[c0] - mu0 * A0;
  float mu1 = psum[c1] * invM;
  float va1 = psq[c1] * invM - mu1 * mu1;
  float A1 = pgamma[c1] * rsqrtf(va1 + EPS_BN);
  float B1 = pbeta[c1] - mu1 * A1;
  float a0 = 0, a1 = 0;
  int cur = gid[n0];
  for (int n = n0; n < n1; n++) {
    int g = gid[n];
    if (g != cur) {
      atomicAdd(&xg[(size_t)cur * 128 + 2 * l], a0);
      atomicAdd(&xg[(size_t)cur * 128 + 2 * l + 1], a1);
      a0 = 0; a1 = 0; cur = g;
    }
    float2 f = unpack2h(y[(size_t)n * 64 + l]);
    a0 += fmaxf(f.x * A0 + B0, 0.f);
    a1 += fmaxf(f.y * A1 + B1, 0.f);
  }
  atomicAdd(&xg[(size_t)cur * 128 + 2 * l], a0);
  atomicAdd(&xg[(size_t)cur * 128 + 2 * l + 1], a1);
}

extern "C" void kernel_launch(void* const* d_in, const int* in_sizes, int n_in,
                              void* d_out, int out_size, void* d_ws, size_t ws_size,
                              hipStream_t stream) {
  const float* h    = (const float*)d_in[0];
  const int*   esrc = (const int*)d_in[1];
  const int*   edst = (const int*)d_in[2];
  const int*   gid  = (const int*)d_in[3];
  const float* W1   = (const float*)d_in[4];
  const float* b1   = (const float*)d_in[5];
  const float* g1g  = (const float*)d_in[6];
  const float* g1b  = (const float*)d_in[7];
  const float* Wg   = (const float*)d_in[8];
  const float* bg   = (const float*)d_in[9];
  const float* gg   = (const float*)d_in[10];
  const float* gb   = (const float*)d_in[11];
  const float* fc1W = (const float*)d_in[12];
  const float* fc1b = (const float*)d_in[13];
  const float* bn1g = (const float*)d_in[14];
  const float* bn1b = (const float*)d_in[15];
  const float* linW = (const float*)d_in[16];
  const float* linb = (const float*)d_in[17];
  const float* lbng = (const float*)d_in[18];
  const float* lbnb = (const float*)d_in[19];
  const float* fc2W = (const float*)d_in[20];
  const float* fc2b = (const float*)d_in[21];
  float* out = (float*)d_out;

  char* p = (char*)d_ws;
  auto alloc = [&](size_t bytes) {
    char* q = p;
    p += (bytes + 255) & ~(size_t)255;
    return q;
  };
  int* row_ptr = (int*)alloc((N_NODES + 1) * sizeof(int));
  int* bcnt    = (int*)alloc(NBUCK * sizeof(int));
  int* bbase   = (int*)alloc((NBUCK + 1) * sizeof(int));
  int* bcur    = (int*)alloc(NBUCK * sizeof(int));
  uint* csrb   = (uint*)alloc(N_EDGES * sizeof(uint));
  uint* hb     = (uint*)alloc((size_t)N_NODES * 64 * sizeof(uint));
  uint* Mb     = (uint*)alloc((size_t)N_NODES * 64 * sizeof(uint));
  uint* yb     = (uint*)alloc((size_t)N_NODES * 64 * sizeof(uint));
  uint* xact   = (uint*)alloc((size_t)N_NODES * 64 * sizeof(uint));
  ushort* Wt   = (ushort*)alloc(5 * 128 * 128 * sizeof(ushort));
  ushort* fc1Wt = (ushort*)alloc(512 * 128 * sizeof(ushort));
  ushort* linWt = (ushort*)alloc(256 * 512 * sizeof(ushort));
  ushort* fc2Wt = (ushort*)alloc(256 * 256 * sizeof(ushort));
  float* stats = (float*)alloc(2816 * sizeof(float));
  float* Ac    = (float*)alloc(512 * sizeof(float));
  float* Bc    = (float*)alloc(512 * sizeof(float));
  float* xg    = (float*)alloc((size_t)N_GRAPHS * 128 * sizeof(float));
  uint* y1b    = (uint*)alloc((size_t)N_GRAPHS * 256 * sizeof(uint));
  uint* y2b    = (uint*)alloc((size_t)N_GRAPHS * 128 * sizeof(uint));
  uint* staging = (uint*)Mb;  // 6.4 MB aliases Mb (dead until layer loop)

  float* lsum = stats;                 // [layer]*256
  float* fsum1 = stats + 1280;         // 512
  float* fsq1  = stats + 1792;         // 512
  float* lsum2 = stats + 2304;         // 256
  float* lsq2  = stats + 2560;         // 256

  // ---- prep: conversions + weights ----
  k_conv_h<<<(N_NODES * 64 + 255) / 256, 256, 0, stream>>>(h, hb, N_NODES);
  {
    dim3 g(64, 5);
    k_prep_wt_all<<<g, 256, 0, stream>>>(W1, Wg, Wt);
  }
  k_prep_wt_gen<<<(512 * 128 + 255) / 256, 256, 0, stream>>>(fc1W, 512, 0, 512, 128, fc1Wt, 512 * 128);
  k_prep_wt_gen<<<(256 * 512 + 255) / 256, 256, 0, stream>>>(linW, 256, 0, 256, 512, linWt, 256 * 512);
  k_prep_wt_gen<<<(256 * 256 + 255) / 256, 256, 0, stream>>>(fc2W, 408, 204, 204, 256, fc2Wt, 256 * 256);

  hipMemsetAsync(stats, 0, 2816 * sizeof(float), stream);
  hipMemsetAsync(xg, 0, (size_t)N_GRAPHS * 128 * sizeof(float), stream);

  // ---- CSR build ----
  hipMemsetAsync(bcnt, 0, NBUCK * sizeof(int), stream);
  k_bin_count<<<(N_EDGES + BIN_CHUNK - 1) / BIN_CHUNK, 256, 0, stream>>>(edst, bcnt, N_EDGES);
  k_bucket_scan<<<1, 512, 0, stream>>>(bcnt, bbase, bcur);
  k_bin<<<(N_EDGES + BIN_CHUNK - 1) / BIN_CHUNK, 256, 0, stream>>>(esrc, edst, bcur,
                                                                   staging, N_EDGES);
  k_place2<<<NBUCK, 256, 0, stream>>>(staging, bbase, row_ptr, csrb, N_NODES, N_EDGES);

  const float invN = 1.0f / (float)N_NODES;
  const float invG = 1.0f / (float)N_GRAPHS;

  // ---- 5 GIN layers: agg (pure sum) -> MFMA GEMM(+stats) -> act (layers 0..3) ----
  for (int layer = 0; layer < 5; layer++) {
    const ushort* Wl = Wt + (size_t)layer * 128 * 128;
    const float* bl  = (layer == 0) ? b1 : bg + (size_t)(layer - 1) * 128;
    const float* gl  = (layer == 0) ? g1g : gg + (size_t)(layer - 1) * 128;
    const float* bl2 = (layer == 0) ? g1b : gb + (size_t)(layer - 1) * 128;
    float* st = lsum + (size_t)layer * 256;

    const char* xin = (layer == 0) ? (const char*)hb : (const char*)xact;
    k_agg<<<(N_NODES + 3) / 4, 256, 0, stream>>>(xin, row_ptr, csrb, (char*)Mb, N_NODES);
    k_gemm_mfma<<<(N_NODES + 127) / 128, 256, 0, stream>>>((const ushort*)Mb, Wl, bl, 2.0f,
                                                           (ushort*)yb, N_NODES,
                                                           st, st + 128);
    if (layer < 4)
      k_act<<<(N_NODES * 16 + 255) / 256, 256, 0, stream>>>((const uint4*)yb,
                                                            st, st + 128, gl, bl2, invN,
                                                            (uint4*)xact, N_NODES * 16);
  }

  // ---- readout (inline layer-5 BN+ReLU) ----
  k_readout<<<(N_NODES + 63) / 64, 64, 0, stream>>>(yb, gid,
                                                    lsum + 4 * 256, lsum + 4 * 256 + 128,
                                                    gg + 3 * 128, gb + 3 * 128, invN,
                                                    xg, N_NODES);

  // ---- fc1 (128 -> 512): fp32 A, fused stats ----
  k_head_mfma<0, 0><<<dim3(4, 16), 256, 0, stream>>>(xg, N_GRAPHS, 128, fc1Wt, fc1b, 0, 512,
                                                     nullptr, nullptr, y1b, 512, fsum1, fsq1);
  k_bnparams<<<1, 512, 0, stream>>>(fsum1, fsq1, bn1g, bn1b, Ac, Bc, 512, invG);

  // ---- lin (512 -> 256): fp16 A + inline bn1/relu, fused stats ----
  k_head_mfma<1, 0><<<dim3(2, 16), 256, 0, stream>>>(y1b, N_GRAPHS, 512, linWt, linb, 0, 256,
                                                     Ac, Bc, y2b, 256, lsum2, lsq2);
  k_bnparams<<<1, 256, 0, stream>>>(lsum2, lsq2, lbng, lbnb, Ac, Bc, 256, invG);

  // ---- fc2 (256 -> 204): fp16 A + inline lbn/relu, sigmoid, write out ----
  k_head_mfma<1, 1><<<dim3(2, 16), 256, 0, stream>>>(y2b, N_GRAPHS, 256, fc2Wt, fc2b, 204, NCLS,
                                                     Ac, Bc, out, NCLS, nullptr, nullptr);
}

// Round 14
// 685.989 us; speedup vs baseline: 1.0941x; 1.0941x over previous
//
#include <hip/hip_runtime.h>
#include <hip/hip_fp16.h>
#include <math.h>

#define N_NODES 100000
#define N_EDGES 1600000
#define N_GRAPHS 2048
#define NCLS 204
#define EPS_BN 1e-5f
#define NBUCK ((N_NODES + 255) / 256)   // 391
#define BIN_CHUNK 8192

typedef __attribute__((ext_vector_type(8))) _Float16 f16x8;
typedef __attribute__((ext_vector_type(4))) float f32x4;

__device__ __forceinline__ uint pack2h(float a, float b) {
  __half2 h = __floats2half2_rn(a, b);
  return *reinterpret_cast<uint*>(&h);
}
__device__ __forceinline__ float2 unpack2h(uint u) {
  __half2 h = *reinterpret_cast<__half2*>(&u);
  return __half22float2(h);
}
__device__ __forceinline__ ushort f2h(float v) {
  __half h = __float2half_rn(v);
  return *reinterpret_cast<ushort*>(&h);
}

// ---------------- CSR build (binned; csr holds BYTE offsets src*256) ----------------
__global__ __launch_bounds__(256) void k_bin_count(const int* __restrict__ dst,
                                                   int* __restrict__ bcnt, int E) {
  __shared__ int hist[NBUCK];
  int t = threadIdx.x;
  int e0 = blockIdx.x * BIN_CHUNK;
  for (int b = t; b < NBUCK; b += 256) hist[b] = 0;
  __syncthreads();
  for (int e = e0 + t; e < min(e0 + BIN_CHUNK, E); e += 256)
    atomicAdd(&hist[dst[e] >> 8], 1);
  __syncthreads();
  for (int b = t; b < NBUCK; b += 256)
    if (hist[b] > 0) atomicAdd(&bcnt[b], hist[b]);
}

__global__ __launch_bounds__(512) void k_bucket_scan(const int* __restrict__ bcnt,
                                                     int* __restrict__ bbase,
                                                     int* __restrict__ bcur) {
  __shared__ int sh[512];
  int t = threadIdx.x;
  int v = (t < NBUCK) ? bcnt[t] : 0;
  sh[t] = v;
  __syncthreads();
  for (int d = 1; d < 512; d <<= 1) {
    int x = (t >= d) ? sh[t - d] : 0;
    __syncthreads();
    sh[t] += x;
    __syncthreads();
  }
  if (t < NBUCK) {
    bbase[t + 1] = sh[t];
    bcur[t] = sh[t] - v;
    if (t == 0) bbase[0] = 0;
  }
}

__global__ __launch_bounds__(256) void k_bin(const int* __restrict__ src,
                                             const int* __restrict__ dst,
                                             int* __restrict__ cursor,
                                             uint* __restrict__ staging, int E) {
  __shared__ int hist[NBUCK];
  __shared__ int base_s[NBUCK];
  int t = threadIdx.x;
  int e0 = blockIdx.x * BIN_CHUNK;
  for (int b = t; b < NBUCK; b += 256) hist[b] = 0;
  __syncthreads();
  for (int e = e0 + t; e < min(e0 + BIN_CHUNK, E); e += 256)
    atomicAdd(&hist[dst[e] >> 8], 1);
  __syncthreads();
  for (int b = t; b < NBUCK; b += 256) {
    int hh = hist[b];
    if (hh > 0) base_s[b] = atomicAdd(&cursor[b], hh);
    hist[b] = 0;
  }
  __syncthreads();
  for (int e = e0 + t; e < min(e0 + BIN_CHUNK, E); e += 256) {
    int d = dst[e];
    int b = d >> 8;
    int r = atomicAdd(&hist[b], 1);
    staging[base_s[b] + r] = (uint)src[e] | ((uint)(d & 255) << 24);
  }
}

__global__ __launch_bounds__(256) void k_place2(const uint* __restrict__ staging,
                                                const int* __restrict__ bbase,
                                                int* __restrict__ row_ptr,
                                                uint* __restrict__ csrb, int nNodes, int E) {
  __shared__ int cnt[256];
  __shared__ int scn[256];
  __shared__ int cur[256];
  int t = threadIdx.x;
  int b = blockIdx.x;
  int n0 = b * 256;
  cnt[t] = 0;
  __syncthreads();
  int s = bbase[b], e = bbase[b + 1];
  for (int i = s + t; i < e; i += 256) atomicAdd(&cnt[staging[i] >> 24], 1);
  __syncthreads();
  int v = cnt[t];
  scn[t] = v;
  __syncthreads();
  for (int d = 1; d < 256; d <<= 1) {
    int x = (t >= d) ? scn[t - d] : 0;
    __syncthreads();
    scn[t] += x;
    __syncthreads();
  }
  int excl = scn[t] - v;
  if (n0 + t < nNodes) row_ptr[n0 + t] = s + excl;
  cur[t] = s + excl;
  __syncthreads();
  for (int i = s + t; i < e; i += 256) {
    uint ed = staging[i];
    int pos = atomicAdd(&cur[ed >> 24], 1);
    csrb[pos] = (ed & 0xFFFFFF) << 8;   // byte offset of src row (256B rows)
  }
  if (b == 0 && t == 0) row_ptr[nNodes] = E;
}

// ---------------- conversions / weight prep (fp16) ----------------
__global__ void k_conv_h(const float* __restrict__ h, uint* __restrict__ hb, int nNodes) {
  int i = blockIdx.x * blockDim.x + threadIdx.x;
  if (i < nNodes * 64) {
    int n = i >> 6, cp = i & 63;
    int c = cp * 2;
    float a = (c < 78) ? h[(size_t)n * 78 + c] : 0.0f;
    float b = (c + 1 < 78) ? h[(size_t)n * 78 + c + 1] : 0.0f;
    hb[i] = pack2h(a, b);
  }
}

__global__ void k_prep_wt_all(const float* __restrict__ W1, const float* __restrict__ Wg,
                              ushort* __restrict__ Wt) {
  int i = blockIdx.x * blockDim.x + threadIdx.x;
  int layer = blockIdx.y;
  if (i < 128 * 128) {
    int n = i >> 7, k = i & 127;
    const float* W = (layer == 0) ? W1 : Wg + (size_t)(layer - 1) * 128 * 128;
    int K = (layer == 0) ? 78 : 128;
    float v = (k < K) ? W[(size_t)k * 128 + n] : 0.0f;
    Wt[(size_t)layer * 128 * 128 + i] = f2h(v);
  }
}

__global__ void k_prep_wt_gen(const float* __restrict__ W, int wld, int col_off, int nkeep,
                              int K, ushort* __restrict__ Wt, int total) {
  int i = blockIdx.x * blockDim.x + threadIdx.x;
  if (i < total) {
    int n = i / K, k = i - n * K;
    float v = (n < nkeep) ? W[(size_t)k * wld + col_off + n] : 0.0f;
    Wt[i] = f2h(v);
  }
}

__global__ void k_bnparams(const float* __restrict__ sum, const float* __restrict__ sumsq,
                           const float* __restrict__ gamma, const float* __restrict__ beta,
                           float* __restrict__ Ac, float* __restrict__ Bc,
                           int C, float invM) {
  int c = blockIdx.x * blockDim.x + threadIdx.x;
  if (c < C) {
    float mu = sum[c] * invM;
    float var = sumsq[c] * invM - mu * mu;
    float rs = rsqrtf(var + EPS_BN);
    float a = gamma[c] * rs;
    Ac[c] = a;
    Bc[c] = beta[c] - mu * a;
  }
}

// ---------------- activation: xact = relu(y*A+B), params computed per-block in LDS ----------------
__global__ __launch_bounds__(256) void k_act(const uint4* __restrict__ y4,
                                             const float* __restrict__ psum,
                                             const float* __restrict__ psq,
                                             const float* __restrict__ pgamma,
                                             const float* __restrict__ pbeta,
                                             float invM,
                                             uint4* __restrict__ x4, int total4) {
  __shared__ float As[128], Bs[128];
  int t = threadIdx.x;
  if (t < 128) {
    float mu = psum[t] * invM;
    float var = psq[t] * invM - mu * mu;
    float a = pgamma[t] * rsqrtf(var + EPS_BN);
    As[t] = a;
    Bs[t] = pbeta[t] - mu * a;
  }
  __syncthreads();
  int i = blockIdx.x * blockDim.x + t;
  if (i < total4) {
    int c = ((i * 4) & 63) * 2;
    float4 A0 = *reinterpret_cast<const float4*>(As + c);
    float4 A1 = *reinterpret_cast<const float4*>(As + c + 4);
    float4 B0 = *reinterpret_cast<const float4*>(Bs + c);
    float4 B1 = *reinterpret_cast<const float4*>(Bs + c + 4);
    uint4 v = y4[i];
    float2 f0 = unpack2h(v.x), f1 = unpack2h(v.y), f2 = unpack2h(v.z), f3 = unpack2h(v.w);
    uint4 o;
    o.x = pack2h(fmaxf(f0.x * A0.x + B0.x, 0.f), fmaxf(f0.y * A0.y + B0.y, 0.f));
    o.y = pack2h(fmaxf(f1.x * A0.z + B0.z, 0.f), fmaxf(f1.y * A0.w + B0.w, 0.f));
    o.z = pack2h(fmaxf(f2.x * A1.x + B1.x, 0.f), fmaxf(f2.y * A1.y + B1.y, 0.f));
    o.w = pack2h(fmaxf(f3.x * A1.z + B1.z, 0.f), fmaxf(f3.y * A1.w + B1.w, 0.f));
    x4[i] = o;
  }
}

// ---------------- GIN aggregation: pure sum, 4-slot dwordx4 gather, 4-deep MLP ----------------
// NOTE: every __shfl executed by ALL lanes (uniform exec) — shfl from an
// exec-masked-off source lane returns 0 on CDNA (round-9 bug).
__global__ __launch_bounds__(256) void k_agg(const char* __restrict__ xraw,
                                             const int* __restrict__ row_ptr,
                                             const uint* __restrict__ csrb,
                                             char* __restrict__ Mraw, int nNodes) {
  int n = blockIdx.x * 4 + (threadIdx.x >> 6);
  if (n >= nNodes) return;
  int l = threadIdx.x & 63;
  int slot = l >> 4;
  int coff = (l & 15) * 16;

  float acc[8];
#pragma unroll
  for (int k = 0; k < 8; k++) acc[k] = 0.f;

  auto accum = [&](uint4 v) {
    float2 f0 = unpack2h(v.x), f1 = unpack2h(v.y), f2 = unpack2h(v.z), f3 = unpack2h(v.w);
    acc[0] += f0.x; acc[1] += f0.y;
    acc[2] += f1.x; acc[3] += f1.y;
    acc[4] += f2.x; acc[5] += f2.y;
    acc[6] += f3.x; acc[7] += f3.y;
  };

  if (slot == 0) {
    uint4 v = *reinterpret_cast<const uint4*>(xraw + (size_t)n * 256 + coff);
    float2 f0 = unpack2h(v.x), f1 = unpack2h(v.y), f2 = unpack2h(v.z), f3 = unpack2h(v.w);
    acc[0] = 2.f * f0.x; acc[1] = 2.f * f0.y;
    acc[2] = 2.f * f1.x; acc[3] = 2.f * f1.y;
    acc[4] = 2.f * f2.x; acc[5] = 2.f * f2.y;
    acc[6] = 2.f * f3.x; acc[7] = 2.f * f3.y;
  }

  int s = row_ptr[n], e = row_ptr[n + 1];
  for (int base = s; base < e; base += 64) {
    int cnt = e - base;
    if (cnt > 64) cnt = 64;
    uint myoff = (base + l < e) ? csrb[base + l] : 0;
    int nfull = cnt >> 2;
    int j = 0;
    for (; j + 4 <= nfull; j += 4) {
      uint o0 = __shfl(myoff, 4 * j + slot);
      uint o1 = __shfl(myoff, 4 * (j + 1) + slot);
      uint o2 = __shfl(myoff, 4 * (j + 2) + slot);
      uint o3 = __shfl(myoff, 4 * (j + 3) + slot);
      uint4 v0 = *reinterpret_cast<const uint4*>(xraw + (size_t)o0 + coff);
      uint4 v1 = *reinterpret_cast<const uint4*>(xraw + (size_t)o1 + coff);
      uint4 v2 = *reinterpret_cast<const uint4*>(xraw + (size_t)o2 + coff);
      uint4 v3 = *reinterpret_cast<const uint4*>(xraw + (size_t)o3 + coff);
      accum(v0); accum(v1); accum(v2); accum(v3);
    }
    for (; j < nfull; j++) {
      uint off = __shfl(myoff, 4 * j + slot);
      uint4 v = *reinterpret_cast<const uint4*>(xraw + (size_t)off + coff);
      accum(v);
    }
    int jj = nfull * 4 + slot;
    uint off = __shfl(myoff, jj < 64 ? jj : 63);
    if (jj < cnt) {
      uint4 v = *reinterpret_cast<const uint4*>(xraw + (size_t)off + coff);
      accum(v);
    }
  }

#pragma unroll
  for (int k = 0; k < 8; k++) {
    acc[k] += __shfl_xor(acc[k], 16);
    acc[k] += __shfl_xor(acc[k], 32);
  }
  if (slot == 0) {
    uint4 o;
    o.x = pack2h(acc[0], acc[1]);
    o.y = pack2h(acc[2], acc[3]);
    o.z = pack2h(acc[4], acc[5]);
    o.w = pack2h(acc[6], acc[7]);
    *reinterpret_cast<uint4*>(Mraw + (size_t)n * 256 + coff) = o;
  }
}

// ---------------- node-layer MFMA GEMM (fp16): A from GLOBAL, B staged in LDS ----------------
// A fragments are directly addressable in global (each A byte read once per block);
// B (32KB) is reused by all 4 waves -> swizzled LDS. LDS total 36KB -> 4 blocks/CU.
#define SWZ(row, boff) ((boff) ^ (((row) & 7) << 4))
__global__ __launch_bounds__(256) void k_gemm_mfma(const ushort* __restrict__ A,
                                                   const ushort* __restrict__ Wt,
                                                   const float* __restrict__ bias, float bscale,
                                                   ushort* __restrict__ Y, int Mrows,
                                                   float* __restrict__ gsum,
                                                   float* __restrict__ gsq) {
  __shared__ ushort Bs[128 * 128];
  __shared__ float sred[4][128], qred[4][128];
  int t = threadIdx.x;
  int r0 = blockIdx.x * 128;
  char* Bb = (char*)Bs;

  // stage B only
  for (int it = 0; it < 8; it++) {
    int e = it * 256 + t;
    int row = e >> 4, seg = e & 15;
    uint4 vb = *reinterpret_cast<const uint4*>(Wt + (size_t)row * 128 + seg * 8);
    *reinterpret_cast<uint4*>(Bb + row * 256 + SWZ(row, seg * 16)) = vb;
  }
  __syncthreads();

  int wi = t >> 6;
  int l = t & 63;
  int lr = l & 15;
  int kp = l >> 4;

  f32x4 acc[2][8];
#pragma unroll
  for (int mi = 0; mi < 2; mi++)
#pragma unroll
    for (int ni = 0; ni < 8; ni++) acc[mi][ni] = (f32x4){0.f, 0.f, 0.f, 0.f};

  const char* Araw = (const char*)A;
#pragma unroll
  for (int ki = 0; ki < 4; ki++) {
    f16x8 a[2], b[8];
#pragma unroll
    for (int mi = 0; mi < 2; mi++) {
      int row = r0 + wi * 32 + mi * 16 + lr;
      // direct global read; OOB rows land in the adjacent ws buffer (stores/stats guarded)
      a[mi] = *reinterpret_cast<const f16x8*>(Araw + (size_t)row * 256 + ki * 64 + kp * 16);
    }
#pragma unroll
    for (int ni = 0; ni < 8; ni++) {
      int row = ni * 16 + lr;
      b[ni] = *reinterpret_cast<const f16x8*>(Bb + row * 256 + SWZ(row, ki * 64 + kp * 16));
    }
#pragma unroll
    for (int mi = 0; mi < 2; mi++)
#pragma unroll
      for (int ni = 0; ni < 8; ni++)
        acc[mi][ni] = __builtin_amdgcn_mfma_f32_16x16x32_f16(a[mi], b[ni], acc[mi][ni], 0, 0, 0);
  }

  float s_part[8], q_part[8];
#pragma unroll
  for (int ni = 0; ni < 8; ni++) { s_part[ni] = 0.f; q_part[ni] = 0.f; }

#pragma unroll
  for (int mi = 0; mi < 2; mi++) {
    int rbase = r0 + wi * 32 + mi * 16 + kp * 4;
#pragma unroll
    for (int ni = 0; ni < 8; ni++) {
      int col = ni * 16 + lr;
      float bb = bscale * bias[col];
#pragma unroll
      for (int j = 0; j < 4; j++) {
        int r = rbase + j;
        if (r < Mrows) {
          float yv = acc[mi][ni][j] + bb;
          Y[(size_t)r * 128 + col] = f2h(yv);
          s_part[ni] += yv;
          q_part[ni] += yv * yv;
        }
      }
    }
  }

#pragma unroll
  for (int ni = 0; ni < 8; ni++) {
    s_part[ni] += __shfl_xor(s_part[ni], 16, 64);
    s_part[ni] += __shfl_xor(s_part[ni], 32, 64);
    q_part[ni] += __shfl_xor(q_part[ni], 16, 64);
    q_part[ni] += __shfl_xor(q_part[ni], 32, 64);
  }
  if (kp == 0) {
#pragma unroll
    for (int ni = 0; ni < 8; ni++) {
      sred[wi][ni * 16 + lr] = s_part[ni];
      qred[wi][ni * 16 + lr] = q_part[ni];
    }
  }
  __syncthreads();
  if (t < 128) {
    float S = sred[0][t] + sred[1][t] + sred[2][t] + sred[3][t];
    float Q = qred[0][t] + qred[1][t] + qred[2][t] + qred[3][t];
    atomicAdd(&gsum[t], S);
    atomicAdd(&gsq[t], Q);
  }
}

// ---------------- head MFMA GEMM (fp16) ----------------
template <int AMODE, int OMODE>
__global__ __launch_bounds__(256) void k_head_mfma(const void* __restrict__ Aptr,
                                                   int Mrows, int K,
                                                   const ushort* __restrict__ Wt,
                                                   const float* __restrict__ bias,
                                                   int col_off, int ncols,
                                                   const float* __restrict__ nAc,
                                                   const float* __restrict__ nBc,
                                                   void* __restrict__ Yout, int Nld,
                                                   float* __restrict__ gsum,
                                                   float* __restrict__ gsq) {
  __shared__ ushort As[128 * 128];
  __shared__ ushort Bs[128 * 128];
  __shared__ float sred[4][128], qred[4][128];
  int t = threadIdx.x;
  int r0 = blockIdx.y * 128;
  int c0 = blockIdx.x * 128;
  char* Ab = (char*)As;
  char* Bb = (char*)Bs;

  int wi = t >> 6;
  int l = t & 63;
  int lr = l & 15;
  int kp = l >> 4;

  f32x4 acc[2][8];
#pragma unroll
  for (int mi = 0; mi < 2; mi++)
#pragma unroll
    for (int ni = 0; ni < 8; ni++) acc[mi][ni] = (f32x4){0.f, 0.f, 0.f, 0.f};

  for (int k0 = 0; k0 < K; k0 += 128) {
    if (k0) __syncthreads();
    for (int it = 0; it < 8; it++) {
      int e = it * 256 + t;
      int row = e >> 4, seg = e & 15;
      int gr = r0 + row;
      uint4 va;
      if (AMODE == 0) {
        const float* Af = (const float*)Aptr;
        float4 f0 = {0.f, 0.f, 0.f, 0.f}, f1 = {0.f, 0.f, 0.f, 0.f};
        if (gr < Mrows) {
          f0 = *reinterpret_cast<const float4*>(Af + (size_t)gr * K + k0 + seg * 8);
          f1 = *reinterpret_cast<const float4*>(Af + (size_t)gr * K + k0 + seg * 8 + 4);
        }
        va.x = pack2h(f0.x, f0.y); va.y = pack2h(f0.z, f0.w);
        va.z = pack2h(f1.x, f1.y); va.w = pack2h(f1.z, f1.w);
      } else {
        const uint* Au = (const uint*)Aptr;
        uint4 r4 = make_uint4(0, 0, 0, 0);
        if (gr < Mrows) r4 = *reinterpret_cast<const uint4*>(Au + (size_t)gr * (K >> 1) + ((k0 + seg * 8) >> 1));
        int c = k0 + seg * 8;
        uint uu[4] = {r4.x, r4.y, r4.z, r4.w};
#pragma unroll
        for (int q = 0; q < 4; q++) {
          float2 f = unpack2h(uu[q]);
          float aa = fmaxf(f.x * nAc[c + 2 * q] + nBc[c + 2 * q], 0.f);
          float bb = fmaxf(f.y * nAc[c + 2 * q + 1] + nBc[c + 2 * q + 1], 0.f);
          uu[q] = pack2h(aa, bb);
        }
        va = make_uint4(uu[0], uu[1], uu[2], uu[3]);
      }
      *reinterpret_cast<uint4*>(Ab + row * 256 + SWZ(row, seg * 16)) = va;
      uint4 vb = *reinterpret_cast<const uint4*>(Wt + (size_t)(c0 + row) * K + k0 + seg * 8);
      *reinterpret_cast<uint4*>(Bb + row * 256 + SWZ(row, seg * 16)) = vb;
    }
    __syncthreads();

#pragma unroll
    for (int ki = 0; ki < 4; ki++) {
      f16x8 a[2], b[8];
#pragma unroll
      for (int mi = 0; mi < 2; mi++) {
        int row = wi * 32 + mi * 16 + lr;
        a[mi] = *reinterpret_cast<const f16x8*>(Ab + row * 256 + SWZ(row, ki * 64 + kp * 16));
      }
#pragma unroll
      for (int ni = 0; ni < 8; ni++) {
        int row = ni * 16 + lr;
        b[ni] = *reinterpret_cast<const f16x8*>(Bb + row * 256 + SWZ(row, ki * 64 + kp * 16));
      }
#pragma unroll
      for (int mi = 0; mi < 2; mi++)
#pragma unroll
        for (int ni = 0; ni < 8; ni++)
          acc[mi][ni] = __builtin_amdgcn_mfma_f32_16x16x32_f16(a[mi], b[ni], acc[mi][ni], 0, 0, 0);
    }
  }

  if (OMODE == 0) {
    float s_part[8], q_part[8];
#pragma unroll
    for (int ni = 0; ni < 8; ni++) { s_part[ni] = 0.f; q_part[ni] = 0.f; }
#pragma unroll
    for (int mi = 0; mi < 2; mi++) {
      int rbase = r0 + wi * 32 + mi * 16 + kp * 4;
#pragma unroll
      for (int ni = 0; ni < 8; ni++) {
        int gc = c0 + ni * 16 + lr;
        float bb = bias[col_off + gc];
#pragma unroll
        for (int j = 0; j < 4; j++) {
          int r = rbase + j;
          if (r < Mrows) {
            float yv = acc[mi][ni][j] + bb;
            ((ushort*)Yout)[(size_t)r * Nld + gc] = f2h(yv);
            s_part[ni] += yv;
            q_part[ni] += yv * yv;
          }
        }
      }
    }
#pragma unroll
    for (int ni = 0; ni < 8; ni++) {
      s_part[ni] += __shfl_xor(s_part[ni], 16, 64);
      s_part[ni] += __shfl_xor(s_part[ni], 32, 64);
      q_part[ni] += __shfl_xor(q_part[ni], 16, 64);
      q_part[ni] += __shfl_xor(q_part[ni], 32, 64);
    }
    if (kp == 0) {
#pragma unroll
      for (int ni = 0; ni < 8; ni++) {
        sred[wi][ni * 16 + lr] = s_part[ni];
        qred[wi][ni * 16 + lr] = q_part[ni];
      }
    }
    __syncthreads();
    if (t < 128) {
      float S = sred[0][t] + sred[1][t] + sred[2][t] + sred[3][t];
      float Q = qred[0][t] + qred[1][t] + qred[2][t] + qred[3][t];
      atomicAdd(&gsum[c0 + t], S);
      atomicAdd(&gsq[c0 + t], Q);
    }
  } else {
#pragma unroll
    for (int mi = 0; mi < 2; mi++) {
      int rbase = r0 + wi * 32 + mi * 16 + kp * 4;
#pragma unroll
      for (int ni = 0; ni < 8; ni++) {
        int gc = c0 + ni * 16 + lr;
        if (gc < ncols) {
          float bb = bias[col_off + gc];
#pragma unroll
          for (int j = 0; j < 4; j++) {
            int r = rbase + j;
            if (r < Mrows) {
              float v = acc[mi][ni][j] + bb;
              ((float*)Yout)[(size_t)r * Nld + gc] = 1.0f / (1.0f + expf(-v));
            }
          }
        }
      }
    }
  }
}

// ---------------- graph readout (fp16 y): xg[g] = sum relu(y*A+B), inline BN params ----------------
__global__ __launch_bounds__(64) void k_readout(const uint* __restrict__ y,
                                                const int* __restrict__ gid,
                                                const float* __restrict__ psum,
                                                const float* __restrict__ psq,
                                                const float* __restrict__ pgamma,
                                                const float* __restrict__ pbeta,
                                                float invM,
                                                float* __restrict__ xg, int nNodes) {
  int l = threadIdx.x;
  int n0 = blockIdx.x * 64;
  int n1 = min(n0 + 64, nNodes);
  if (n0 >= nNodes) return;
  int c0 = 2 * l, c1 = 2 * l + 1;
  float mu0 = psum[c0] * invM;
  float va0 = psq[c0] * invM - mu0 * mu0;
  float A0 = pgamma[c0] * rsqrtf(va0 + EPS_BN);
  float B0 = pbeta[c0] - mu0 * A0;
  float mu1 = psum[c1] * invM;
  float va1 = psq[c1] * invM - mu1 * mu1;
  float A1 = pgamma[c1] * rsqrtf(va1 + EPS_BN);
  float B1 = pbeta[c1] - mu1 * A1;
  float a0 = 0, a1 = 0;
  int cur = gid[n0];
  for (int n = n0; n < n1; n++) {
    int g = gid[n];
    if (g != cur) {
      atomicAdd(&xg[(size_t)cur * 128 + 2 * l], a0);
      atomicAdd(&xg[(size_t)cur * 128 + 2 * l + 1], a1);
      a0 = 0; a1 = 0; cur = g;
    }
    float2 f = unpack2h(y[(size_t)n * 64 + l]);
    a0 += fmaxf(f.x * A0 + B0, 0.f);
    a1 += fmaxf(f.y * A1 + B1, 0.f);
  }
  atomicAdd(&xg[(size_t)cur * 128 + 2 * l], a0);
  atomicAdd(&xg[(size_t)cur * 128 + 2 * l + 1], a1);
}

extern "C" void kernel_launch(void* const* d_in, const int* in_sizes, int n_in,
                              void* d_out, int out_size, void* d_ws, size_t ws_size,
                              hipStream_t stream) {
  const float* h    = (const float*)d_in[0];
  const int*   esrc = (const int*)d_in[1];
  const int*   edst = (const int*)d_in[2];
  const int*   gid  = (const int*)d_in[3];
  const float* W1   = (const float*)d_in[4];
  const float* b1   = (const float*)d_in[5];
  const float* g1g  = (const float*)d_in[6];
  const float* g1b  = (const float*)d_in[7];
  const float* Wg   = (const float*)d_in[8];
  const float* bg   = (const float*)d_in[9];
  const float* gg   = (const float*)d_in[10];
  const float* gb   = (const float*)d_in[11];
  const float* fc1W = (const float*)d_in[12];
  const float* fc1b = (const float*)d_in[13];
  const float* bn1g = (const float*)d_in[14];
  const float* bn1b = (const float*)d_in[15];
  const float* linW = (const float*)d_in[16];
  const float* linb = (const float*)d_in[17];
  const float* lbng = (const float*)d_in[18];
  const float* lbnb = (const float*)d_in[19];
  const float* fc2W = (const float*)d_in[20];
  const float* fc2b = (const float*)d_in[21];
  float* out = (float*)d_out;

  char* p = (char*)d_ws;
  auto alloc = [&](size_t bytes) {
    char* q = p;
    p += (bytes + 255) & ~(size_t)255;
    return q;
  };
  int* row_ptr = (int*)alloc((N_NODES + 1) * sizeof(int));
  int* bcnt    = (int*)alloc(NBUCK * sizeof(int));
  int* bbase   = (int*)alloc((NBUCK + 1) * sizeof(int));
  int* bcur    = (int*)alloc(NBUCK * sizeof(int));
  uint* csrb   = (uint*)alloc(N_EDGES * sizeof(uint));
  uint* hb     = (uint*)alloc((size_t)N_NODES * 64 * sizeof(uint));
  uint* Mb     = (uint*)alloc((size_t)N_NODES * 64 * sizeof(uint) + 32768);  // +pad for OOB A reads
  uint* yb     = (uint*)alloc((size_t)N_NODES * 64 * sizeof(uint));
  uint* xact   = (uint*)alloc((size_t)N_NODES * 64 * sizeof(uint));
  ushort* Wt   = (ushort*)alloc(5 * 128 * 128 * sizeof(ushort));
  ushort* fc1Wt = (ushort*)alloc(512 * 128 * sizeof(ushort));
  ushort* linWt = (ushort*)alloc(256 * 512 * sizeof(ushort));
  ushort* fc2Wt = (ushort*)alloc(256 * 256 * sizeof(ushort));
  float* stats = (float*)alloc(2816 * sizeof(float));
  float* Ac    = (float*)alloc(512 * sizeof(float));
  float* Bc    = (float*)alloc(512 * sizeof(float));
  float* xg    = (float*)alloc((size_t)N_GRAPHS * 128 * sizeof(float));
  uint* y1b    = (uint*)alloc((size_t)N_GRAPHS * 256 * sizeof(uint));
  uint* y2b    = (uint*)alloc((size_t)N_GRAPHS * 128 * sizeof(uint));
  uint* staging = (uint*)Mb;  // 6.4 MB aliases Mb (dead until layer loop)

  float* lsum = stats;                 // [layer]*256
  float* fsum1 = stats + 1280;         // 512
  float* fsq1  = stats + 1792;         // 512
  float* lsum2 = stats + 2304;         // 256
  float* lsq2  = stats + 2560;         // 256

  // ---- prep: conversions + weights ----
  k_conv_h<<<(N_NODES * 64 + 255) / 256, 256, 0, stream>>>(h, hb, N_NODES);
  {
    dim3 g(64, 5);
    k_prep_wt_all<<<g, 256, 0, stream>>>(W1, Wg, Wt);
  }
  k_prep_wt_gen<<<(512 * 128 + 255) / 256, 256, 0, stream>>>(fc1W, 512, 0, 512, 128, fc1Wt, 512 * 128);
  k_prep_wt_gen<<<(256 * 512 + 255) / 256, 256, 0, stream>>>(linW, 256, 0, 256, 512, linWt, 256 * 512);
  k_prep_wt_gen<<<(256 * 256 + 255) / 256, 256, 0, stream>>>(fc2W, 408, 204, 204, 256, fc2Wt, 256 * 256);

  hipMemsetAsync(stats, 0, 2816 * sizeof(float), stream);
  hipMemsetAsync(xg, 0, (size_t)N_GRAPHS * 128 * sizeof(float), stream);

  // ---- CSR build ----
  hipMemsetAsync(bcnt, 0, NBUCK * sizeof(int), stream);
  k_bin_count<<<(N_EDGES + BIN_CHUNK - 1) / BIN_CHUNK, 256, 0, stream>>>(edst, bcnt, N_EDGES);
  k_bucket_scan<<<1, 512, 0, stream>>>(bcnt, bbase, bcur);
  k_bin<<<(N_EDGES + BIN_CHUNK - 1) / BIN_CHUNK, 256, 0, stream>>>(esrc, edst, bcur,
                                                                   staging, N_EDGES);
  k_place2<<<NBUCK, 256, 0, stream>>>(staging, bbase, row_ptr, csrb, N_NODES, N_EDGES);

  const float invN = 1.0f / (float)N_NODES;
  const float invG = 1.0f / (float)N_GRAPHS;

  // ---- 5 GIN layers: agg (pure sum) -> MFMA GEMM(+stats) -> act (layers 0..3) ----
  for (int layer = 0; layer < 5; layer++) {
    const ushort* Wl = Wt + (size_t)layer * 128 * 128;
    const float* bl  = (layer == 0) ? b1 : bg + (size_t)(layer - 1) * 128;
    const float* gl  = (layer == 0) ? g1g : gg + (size_t)(layer - 1) * 128;
    const float* bl2 = (layer == 0) ? g1b : gb + (size_t)(layer - 1) * 128;
    float* st = lsum + (size_t)layer * 256;

    const char* xin = (layer == 0) ? (const char*)hb : (const char*)xact;
    k_agg<<<(N_NODES + 3) / 4, 256, 0, stream>>>(xin, row_ptr, csrb, (char*)Mb, N_NODES);
    k_gemm_mfma<<<(N_NODES + 127) / 128, 256, 0, stream>>>((const ushort*)Mb, Wl, bl, 2.0f,
                                                           (ushort*)yb, N_NODES,
                                                           st, st + 128);
    if (layer < 4)
      k_act<<<(N_NODES * 16 + 255) / 256, 256, 0, stream>>>((const uint4*)yb,
                                                            st, st + 128, gl, bl2, invN,
                                                            (uint4*)xact, N_NODES * 16);
  }

  // ---- readout (inline layer-5 BN+ReLU) ----
  k_readout<<<(N_NODES + 63) / 64, 64, 0, stream>>>(yb, gid,
                                                    lsum + 4 * 256, lsum + 4 * 256 + 128,
                                                    gg + 3 * 128, gb + 3 * 128, invN,
                                                    xg, N_NODES);

  // ---- fc1 (128 -> 512): fp32 A, fused stats ----
  k_head_mfma<0, 0><<<dim3(4, 16), 256, 0, stream>>>(xg, N_GRAPHS, 128, fc1Wt, fc1b, 0, 512,
                                                     nullptr, nullptr, y1b, 512, fsum1, fsq1);
  k_bnparams<<<1, 512, 0, stream>>>(fsum1, fsq1, bn1g, bn1b, Ac, Bc, 512, invG);

  // ---- lin (512 -> 256): fp16 A + inline bn1/relu, fused stats ----
  k_head_mfma<1, 0><<<dim3(2, 16), 256, 0, stream>>>(y1b, N_GRAPHS, 512, linWt, linb, 0, 256,
                                                     Ac, Bc, y2b, 256, lsum2, lsq2);
  k_bnparams<<<1, 256, 0, stream>>>(lsum2, lsq2, lbng, lbnb, Ac, Bc, 256, invG);

  // ---- fc2 (256 -> 204): fp16 A + inline lbn/relu, sigmoid, write out ----
  k_head_mfma<1, 1><<<dim3(2, 16), 256, 0, stream>>>(y2b, N_GRAPHS, 256, fc2Wt, fc2b, 204, NCLS,
                                                     Ac, Bc, out, NCLS, nullptr, nullptr);
}

// Round 16
// 657.152 us; speedup vs baseline: 1.1421x; 1.0439x over previous
//
#include <hip/hip_runtime.h>
#include <hip/hip_fp16.h>
#include <math.h>

#define N_NODES 100000
#define N_EDGES 1600000
#define N_GRAPHS 2048
#define NCLS 204
#define EPS_BN 1e-5f
#define NBUCK ((N_NODES + 255) / 256)   // 391
#define BIN_CHUNK 8192

typedef __attribute__((ext_vector_type(8))) _Float16 f16x8;
typedef __attribute__((ext_vector_type(4))) float f32x4;

__device__ __forceinline__ uint pack2h(float a, float b) {
  __half2 h = __floats2half2_rn(a, b);
  return *reinterpret_cast<uint*>(&h);
}
__device__ __forceinline__ float2 unpack2h(uint u) {
  __half2 h = *reinterpret_cast<__half2*>(&u);
  return __half22float2(h);
}
__device__ __forceinline__ ushort f2h(float v) {
  __half h = __float2half_rn(v);
  return *reinterpret_cast<ushort*>(&h);
}

// ---------------- CSR build (binned; csrb holds BYTE offsets src*256) ----------------
__global__ __launch_bounds__(256) void k_bin_count(const int* __restrict__ dst,
                                                   int* __restrict__ bcnt, int E) {
  __shared__ int hist[NBUCK];
  int t = threadIdx.x;
  int e0 = blockIdx.x * BIN_CHUNK;
  for (int b = t; b < NBUCK; b += 256) hist[b] = 0;
  __syncthreads();
  for (int e = e0 + t; e < min(e0 + BIN_CHUNK, E); e += 256)
    atomicAdd(&hist[dst[e] >> 8], 1);
  __syncthreads();
  for (int b = t; b < NBUCK; b += 256)
    if (hist[b] > 0) atomicAdd(&bcnt[b], hist[b]);
}

__global__ __launch_bounds__(512) void k_bucket_scan(const int* __restrict__ bcnt,
                                                     int* __restrict__ bbase,
                                                     int* __restrict__ bcur) {
  __shared__ int sh[512];
  int t = threadIdx.x;
  int v = (t < NBUCK) ? bcnt[t] : 0;
  sh[t] = v;
  __syncthreads();
  for (int d = 1; d < 512; d <<= 1) {
    int x = (t >= d) ? sh[t - d] : 0;
    __syncthreads();
    sh[t] += x;
    __syncthreads();
  }
  if (t < NBUCK) {
    bbase[t + 1] = sh[t];
    bcur[t] = sh[t] - v;
    if (t == 0) bbase[0] = 0;
  }
}

__global__ __launch_bounds__(256) void k_bin(const int* __restrict__ src,
                                             const int* __restrict__ dst,
                                             int* __restrict__ cursor,
                                             uint* __restrict__ staging, int E) {
  __shared__ int hist[NBUCK];
  __shared__ int base_s[NBUCK];
  int t = threadIdx.x;
  int e0 = blockIdx.x * BIN_CHUNK;
  for (int b = t; b < NBUCK; b += 256) hist[b] = 0;
  __syncthreads();
  for (int e = e0 + t; e < min(e0 + BIN_CHUNK, E); e += 256)
    atomicAdd(&hist[dst[e] >> 8], 1);
  __syncthreads();
  for (int b = t; b < NBUCK; b += 256) {
    int hh = hist[b];
    if (hh > 0) base_s[b] = atomicAdd(&cursor[b], hh);
    hist[b] = 0;
  }
  __syncthreads();
  for (int e = e0 + t; e < min(e0 + BIN_CHUNK, E); e += 256) {
    int d = dst[e];
    int b = d >> 8;
    int r = atomicAdd(&hist[b], 1);
    staging[base_s[b] + r] = (uint)src[e] | ((uint)(d & 255) << 24);
  }
}

__global__ __launch_bounds__(256) void k_place2(const uint* __restrict__ staging,
                                                const int* __restrict__ bbase,
                                                int* __restrict__ row_ptr,
                                                uint* __restrict__ csrb, int nNodes, int E) {
  __shared__ int cnt[256];
  __shared__ int scn[256];
  __shared__ int cur[256];
  int t = threadIdx.x;
  int b = blockIdx.x;
  int n0 = b * 256;
  cnt[t] = 0;
  __syncthreads();
  int s = bbase[b], e = bbase[b + 1];
  for (int i = s + t; i < e; i += 256) atomicAdd(&cnt[staging[i] >> 24], 1);
  __syncthreads();
  int v = cnt[t];
  scn[t] = v;
  __syncthreads();
  for (int d = 1; d < 256; d <<= 1) {
    int x = (t >= d) ? scn[t - d] : 0;
    __syncthreads();
    scn[t] += x;
    __syncthreads();
  }
  int excl = scn[t] - v;
  if (n0 + t < nNodes) row_ptr[n0 + t] = s + excl;
  cur[t] = s + excl;
  __syncthreads();
  for (int i = s + t; i < e; i += 256) {
    uint ed = staging[i];
    int pos = atomicAdd(&cur[ed >> 24], 1);
    csrb[pos] = (ed & 0xFFFFFF) << 8;   // byte offset of src row (256B rows)
  }
  if (b == 0 && t == 0) row_ptr[nNodes] = E;
}

// ---------------- conversions / weight prep (fp16) ----------------
__global__ void k_conv_h(const float* __restrict__ h, uint* __restrict__ hb, int nNodes) {
  int i = blockIdx.x * blockDim.x + threadIdx.x;
  if (i < nNodes * 64) {
    int n = i >> 6, cp = i & 63;
    int c = cp * 2;
    float a = (c < 78) ? h[(size_t)n * 78 + c] : 0.0f;
    float b = (c + 1 < 78) ? h[(size_t)n * 78 + c + 1] : 0.0f;
    hb[i] = pack2h(a, b);
  }
}

__global__ void k_prep_wt_all(const float* __restrict__ W1, const float* __restrict__ Wg,
                              ushort* __restrict__ Wt) {
  int i = blockIdx.x * blockDim.x + threadIdx.x;
  int layer = blockIdx.y;
  if (i < 128 * 128) {
    int n = i >> 7, k = i & 127;
    const float* W = (layer == 0) ? W1 : Wg + (size_t)(layer - 1) * 128 * 128;
    int K = (layer == 0) ? 78 : 128;
    float v = (k < K) ? W[(size_t)k * 128 + n] : 0.0f;
    Wt[(size_t)layer * 128 * 128 + i] = f2h(v);
  }
}

__global__ void k_prep_wt_gen(const float* __restrict__ W, int wld, int col_off, int nkeep,
                              int K, ushort* __restrict__ Wt, int total) {
  int i = blockIdx.x * blockDim.x + threadIdx.x;
  if (i < total) {
    int n = i / K, k = i - n * K;
    float v = (n < nkeep) ? W[(size_t)k * wld + col_off + n] : 0.0f;
    Wt[i] = f2h(v);
  }
}

__global__ void k_bnparams(const float* __restrict__ sum, const float* __restrict__ sumsq,
                           const float* __restrict__ gamma, const float* __restrict__ beta,
                           float* __restrict__ Ac, float* __restrict__ Bc,
                           int C, float invM) {
  int c = blockIdx.x * blockDim.x + threadIdx.x;
  if (c < C) {
    float mu = sum[c] * invM;
    float var = sumsq[c] * invM - mu * mu;
    float rs = rsqrtf(var + EPS_BN);
    float a = gamma[c] * rs;
    Ac[c] = a;
    Bc[c] = beta[c] - mu * a;
  }
}

// ---------------- GIN aggregation with inline prev-layer BN+ReLU (packed fp16 math) ----------------
// 64 lanes per node-row (4B/lane), fp32 accum, csrb byte offsets, 4-deep gather.
// Wave-uniform loop bounds -> shfl always reads active lanes (safe).
template <bool NRM>
__global__ __launch_bounds__(256) void k_agg_f(const uint* __restrict__ y,
                                               const int* __restrict__ row_ptr,
                                               const uint* __restrict__ csrb,
                                               const float* __restrict__ psum,
                                               const float* __restrict__ psq,
                                               const float* __restrict__ pgamma,
                                               const float* __restrict__ pbeta,
                                               float invM,
                                               uint* __restrict__ M, int nNodes) {
  int n = blockIdx.x * 4 + (threadIdx.x >> 6);
  if (n >= nNodes) return;
  int l = threadIdx.x & 63;
  int loff = l * 4;
  const char* yraw = (const char*)y;

  __half2 An, Bn;
  if (NRM) {
    int c0 = 2 * l, c1 = c0 + 1;
    float mu0 = psum[c0] * invM;
    float A0 = pgamma[c0] * rsqrtf(psq[c0] * invM - mu0 * mu0 + EPS_BN);
    float B0 = pbeta[c0] - mu0 * A0;
    float mu1 = psum[c1] * invM;
    float A1 = pgamma[c1] * rsqrtf(psq[c1] * invM - mu1 * mu1 + EPS_BN);
    float B1 = pbeta[c1] - mu1 * A1;
    An = __floats2half2_rn(A0, A1);
    Bn = __floats2half2_rn(B0, B1);
  }
  const __half2 z2 = __floats2half2_rn(0.f, 0.f);

  auto fval = [&](uint v) -> float2 {
    __half2 hv = *reinterpret_cast<__half2*>(&v);
    if (NRM) {
      hv = __hfma2(hv, An, Bn);          // v_pk_fma_f16
      hv = __hmul2(hv, __hgt2(hv, z2));  // packed relu: x * (x>0)
    }
    return __half22float2(hv);
  };

  uint self = *reinterpret_cast<const uint*>(yraw + (size_t)n * 256 + loff);
  float2 fs = fval(self);
  float a0 = 2.f * fs.x, a1 = 2.f * fs.y;

  int s = row_ptr[n], e = row_ptr[n + 1];
  for (int base = s; base < e; base += 64) {
    int cnt = e - base;
    if (cnt > 64) cnt = 64;
    uint myoff = (base + l < e) ? csrb[base + l] : 0;
    int j = 0;
    for (; j + 4 <= cnt; j += 4) {
      uint o0 = __shfl(myoff, j);
      uint o1 = __shfl(myoff, j + 1);
      uint o2 = __shfl(myoff, j + 2);
      uint o3 = __shfl(myoff, j + 3);
      uint v0 = *reinterpret_cast<const uint*>(yraw + (size_t)o0 + loff);
      uint v1 = *reinterpret_cast<const uint*>(yraw + (size_t)o1 + loff);
      uint v2 = *reinterpret_cast<const uint*>(yraw + (size_t)o2 + loff);
      uint v3 = *reinterpret_cast<const uint*>(yraw + (size_t)o3 + loff);
      float2 f0 = fval(v0), f1 = fval(v1), f2 = fval(v2), f3 = fval(v3);
      a0 += f0.x + f1.x + f2.x + f3.x;
      a1 += f0.y + f1.y + f2.y + f3.y;
    }
    for (; j < cnt; j++) {
      uint o = __shfl(myoff, j);
      uint v = *reinterpret_cast<const uint*>(yraw + (size_t)o + loff);
      float2 f = fval(v);
      a0 += f.x;
      a1 += f.y;
    }
  }
  M[(size_t)n * 64 + l] = pack2h(a0, a1);
}

// ---------------- node-layer MFMA GEMM (fp16, A+B in swizzled LDS) + fused BN stats ----------------
#define SWZ(row, boff) ((boff) ^ (((row) & 7) << 4))
__global__ __launch_bounds__(256) void k_gemm_mfma(const ushort* __restrict__ A,
                                                   const ushort* __restrict__ Wt,
                                                   const float* __restrict__ bias, float bscale,
                                                   ushort* __restrict__ Y, int Mrows,
                                                   float* __restrict__ gsum,
                                                   float* __restrict__ gsq) {
  __shared__ ushort As[128 * 128];
  __shared__ ushort Bs[128 * 128];
  __shared__ float sred[4][128], qred[4][128];
  int t = threadIdx.x;
  int r0 = blockIdx.x * 128;
  char* Ab = (char*)As;
  char* Bb = (char*)Bs;

  for (int it = 0; it < 8; it++) {
    int e = it * 256 + t;
    int row = e >> 4, seg = e & 15;
    uint4 va = make_uint4(0, 0, 0, 0);
    int gr = r0 + row;
    if (gr < Mrows) va = *reinterpret_cast<const uint4*>(A + (size_t)gr * 128 + seg * 8);
    *reinterpret_cast<uint4*>(Ab + row * 256 + SWZ(row, seg * 16)) = va;
    uint4 vb = *reinterpret_cast<const uint4*>(Wt + (size_t)row * 128 + seg * 8);
    *reinterpret_cast<uint4*>(Bb + row * 256 + SWZ(row, seg * 16)) = vb;
  }
  __syncthreads();

  int wi = t >> 6;
  int l = t & 63;
  int lr = l & 15;
  int kp = l >> 4;

  f32x4 acc[2][8];
#pragma unroll
  for (int mi = 0; mi < 2; mi++)
#pragma unroll
    for (int ni = 0; ni < 8; ni++) acc[mi][ni] = (f32x4){0.f, 0.f, 0.f, 0.f};

#pragma unroll
  for (int ki = 0; ki < 4; ki++) {
    f16x8 a[2], b[8];
#pragma unroll
    for (int mi = 0; mi < 2; mi++) {
      int row = wi * 32 + mi * 16 + lr;
      a[mi] = *reinterpret_cast<const f16x8*>(Ab + row * 256 + SWZ(row, ki * 64 + kp * 16));
    }
#pragma unroll
    for (int ni = 0; ni < 8; ni++) {
      int row = ni * 16 + lr;
      b[ni] = *reinterpret_cast<const f16x8*>(Bb + row * 256 + SWZ(row, ki * 64 + kp * 16));
    }
#pragma unroll
    for (int mi = 0; mi < 2; mi++)
#pragma unroll
      for (int ni = 0; ni < 8; ni++)
        acc[mi][ni] = __builtin_amdgcn_mfma_f32_16x16x32_f16(a[mi], b[ni], acc[mi][ni], 0, 0, 0);
  }

  float s_part[8], q_part[8];
#pragma unroll
  for (int ni = 0; ni < 8; ni++) { s_part[ni] = 0.f; q_part[ni] = 0.f; }

#pragma unroll
  for (int mi = 0; mi < 2; mi++) {
    int rbase = r0 + wi * 32 + mi * 16 + kp * 4;
#pragma unroll
    for (int ni = 0; ni < 8; ni++) {
      int col = ni * 16 + lr;
      float bb = bscale * bias[col];
#pragma unroll
      for (int j = 0; j < 4; j++) {
        int r = rbase + j;
        if (r < Mrows) {
          float yv = acc[mi][ni][j] + bb;
          Y[(size_t)r * 128 + col] = f2h(yv);
          s_part[ni] += yv;
          q_part[ni] += yv * yv;
        }
      }
    }
  }

#pragma unroll
  for (int ni = 0; ni < 8; ni++) {
    s_part[ni] += __shfl_xor(s_part[ni], 16, 64);
    s_part[ni] += __shfl_xor(s_part[ni], 32, 64);
    q_part[ni] += __shfl_xor(q_part[ni], 16, 64);
    q_part[ni] += __shfl_xor(q_part[ni], 32, 64);
  }
  if (kp == 0) {
#pragma unroll
    for (int ni = 0; ni < 8; ni++) {
      sred[wi][ni * 16 + lr] = s_part[ni];
      qred[wi][ni * 16 + lr] = q_part[ni];
    }
  }
  __syncthreads();
  if (t < 128) {
    float S = sred[0][t] + sred[1][t] + sred[2][t] + sred[3][t];
    float Q = qred[0][t] + qred[1][t] + qred[2][t] + qred[3][t];
    atomicAdd(&gsum[t], S);
    atomicAdd(&gsq[t], Q);
  }
}

// ---------------- head MFMA GEMM (fp16) ----------------
template <int AMODE, int OMODE>
__global__ __launch_bounds__(256) void k_head_mfma(const void* __restrict__ Aptr,
                                                   int Mrows, int K,
                                                   const ushort* __restrict__ Wt,
                                                   const float* __restrict__ bias,
                                                   int col_off, int ncols,
                                                   const float* __restrict__ nAc,
                                                   const float* __restrict__ nBc,
                                                   void* __restrict__ Yout, int Nld,
                                                   float* __restrict__ gsum,
                                                   float* __restrict__ gsq) {
  __shared__ ushort As[128 * 128];
  __shared__ ushort Bs[128 * 128];
  __shared__ float sred[4][128], qred[4][128];
  int t = threadIdx.x;
  int r0 = blockIdx.y * 128;
  int c0 = blockIdx.x * 128;
  char* Ab = (char*)As;
  char* Bb = (char*)Bs;

  int wi = t >> 6;
  int l = t & 63;
  int lr = l & 15;
  int kp = l >> 4;

  f32x4 acc[2][8];
#pragma unroll
  for (int mi = 0; mi < 2; mi++)
#pragma unroll
    for (int ni = 0; ni < 8; ni++) acc[mi][ni] = (f32x4){0.f, 0.f, 0.f, 0.f};

  for (int k0 = 0; k0 < K; k0 += 128) {
    if (k0) __syncthreads();
    for (int it = 0; it < 8; it++) {
      int e = it * 256 + t;
      int row = e >> 4, seg = e & 15;
      int gr = r0 + row;
      uint4 va;
      if (AMODE == 0) {
        const float* Af = (const float*)Aptr;
        float4 f0 = {0.f, 0.f, 0.f, 0.f}, f1 = {0.f, 0.f, 0.f, 0.f};
        if (gr < Mrows) {
          f0 = *reinterpret_cast<const float4*>(Af + (size_t)gr * K + k0 + seg * 8);
          f1 = *reinterpret_cast<const float4*>(Af + (size_t)gr * K + k0 + seg * 8 + 4);
        }
        va.x = pack2h(f0.x, f0.y); va.y = pack2h(f0.z, f0.w);
        va.z = pack2h(f1.x, f1.y); va.w = pack2h(f1.z, f1.w);
      } else {
        const uint* Au = (const uint*)Aptr;
        uint4 r4 = make_uint4(0, 0, 0, 0);
        if (gr < Mrows) r4 = *reinterpret_cast<const uint4*>(Au + (size_t)gr * (K >> 1) + ((k0 + seg * 8) >> 1));
        int c = k0 + seg * 8;
        uint uu[4] = {r4.x, r4.y, r4.z, r4.w};
#pragma unroll
        for (int q = 0; q < 4; q++) {
          float2 f = unpack2h(uu[q]);
          float aa = fmaxf(f.x * nAc[c + 2 * q] + nBc[c + 2 * q], 0.f);
          float bb = fmaxf(f.y * nAc[c + 2 * q + 1] + nBc[c + 2 * q + 1], 0.f);
          uu[q] = pack2h(aa, bb);
        }
        va = make_uint4(uu[0], uu[1], uu[2], uu[3]);
      }
      *reinterpret_cast<uint4*>(Ab + row * 256 + SWZ(row, seg * 16)) = va;
      uint4 vb = *reinterpret_cast<const uint4*>(Wt + (size_t)(c0 + row) * K + k0 + seg * 8);
      *reinterpret_cast<uint4*>(Bb + row * 256 + SWZ(row, seg * 16)) = vb;
    }
    __syncthreads();

#pragma unroll
    for (int ki = 0; ki < 4; ki++) {
      f16x8 a[2], b[8];
#pragma unroll
      for (int mi = 0; mi < 2; mi++) {
        int row = wi * 32 + mi * 16 + lr;
        a[mi] = *reinterpret_cast<const f16x8*>(Ab + row * 256 + SWZ(row, ki * 64 + kp * 16));
      }
#pragma unroll
      for (int ni = 0; ni < 8; ni++) {
        int row = ni * 16 + lr;
        b[ni] = *reinterpret_cast<const f16x8*>(Bb + row * 256 + SWZ(row, ki * 64 + kp * 16));
      }
#pragma unroll
      for (int mi = 0; mi < 2; mi++)
#pragma unroll
        for (int ni = 0; ni < 8; ni++)
          acc[mi][ni] = __builtin_amdgcn_mfma_f32_16x16x32_f16(a[mi], b[ni], acc[mi][ni], 0, 0, 0);
    }
  }

  if (OMODE == 0) {
    float s_part[8], q_part[8];
#pragma unroll
    for (int ni = 0; ni < 8; ni++) { s_part[ni] = 0.f; q_part[ni] = 0.f; }
#pragma unroll
    for (int mi = 0; mi < 2; mi++) {
      int rbase = r0 + wi * 32 + mi * 16 + kp * 4;
#pragma unroll
      for (int ni = 0; ni < 8; ni++) {
        int gc = c0 + ni * 16 + lr;
        float bb = bias[col_off + gc];
#pragma unroll
        for (int j = 0; j < 4; j++) {
          int r = rbase + j;
          if (r < Mrows) {
            float yv = acc[mi][ni][j] + bb;
            ((ushort*)Yout)[(size_t)r * Nld + gc] = f2h(yv);
            s_part[ni] += yv;
            q_part[ni] += yv * yv;
          }
        }
      }
    }
#pragma unroll
    for (int ni = 0; ni < 8; ni++) {
      s_part[ni] += __shfl_xor(s_part[ni], 16, 64);
      s_part[ni] += __shfl_xor(s_part[ni], 32, 64);
      q_part[ni] += __shfl_xor(q_part[ni], 16, 64);
      q_part[ni] += __shfl_xor(q_part[ni], 32, 64);
    }
    if (kp == 0) {
#pragma unroll
      for (int ni = 0; ni < 8; ni++) {
        sred[wi][ni * 16 + lr] = s_part[ni];
        qred[wi][ni * 16 + lr] = q_part[ni];
      }
    }
    __syncthreads();
    if (t < 128) {
      float S = sred[0][t] + sred[1][t] + sred[2][t] + sred[3][t];
      float Q = qred[0][t] + qred[1][t] + qred[2][t] + qred[3][t];
      atomicAdd(&gsum[c0 + t], S);
      atomicAdd(&gsq[c0 + t], Q);
    }
  } else {
#pragma unroll
    for (int mi = 0; mi < 2; mi++) {
      int rbase = r0 + wi * 32 + mi * 16 + kp * 4;
#pragma unroll
      for (int ni = 0; ni < 8; ni++) {
        int gc = c0 + ni * 16 + lr;
        if (gc < ncols) {
          float bb = bias[col_off + gc];
#pragma unroll
          for (int j = 0; j < 4; j++) {
            int r = rbase + j;
            if (r < Mrows) {
              float v = acc[mi][ni][j] + bb;
              ((float*)Yout)[(size_t)r * Nld + gc] = 1.0f / (1.0f + expf(-v));
            }
          }
        }
      }
    }
  }
}

// ---------------- graph readout (fp16 y): xg[g] = sum relu(y*A+B), inline BN params ----------------
__global__ __launch_bounds__(64) void k_readout(const uint* __restrict__ y,
                                                const int* __restrict__ gid,
                                                const float* __restrict__ psum,
                                                const float* __restrict__ psq,
                                                const float* __restrict__ pgamma,
                                                const float* __restrict__ pbeta,
                                                float invM,
                                                float* __restrict__ xg, int nNodes) {
  int l = threadIdx.x;
  int n0 = blockIdx.x * 64;
  int n1 = min(n0 + 64, nNodes);
  if (n0 >= nNodes) return;
  int c0 = 2 * l, c1 = 2 * l + 1;
  float mu0 = psum[c0] * invM;
  float va0 = psq[c0] * invM - mu0 * mu0;
  float A0 = pgamma[c0] * rsqrtf(va0 + EPS_BN);
  float B0 = pbeta[c0] - mu0 * A0;
  float mu1 = psum[c1] * invM;
  float va1 = psq[c1] * invM - mu1 * mu1;
  float A1 = pgamma[c1] * rsqrtf(va1 + EPS_BN);
  float B1 = pbeta[c1] - mu1 * A1;
  float a0 = 0, a1 = 0;
  int cur = gid[n0];
  for (int n = n0; n < n1; n++) {
    int g = gid[n];
    if (g != cur) {
      atomicAdd(&xg[(size_t)cur * 128 + 2 * l], a0);
      atomicAdd(&xg[(size_t)cur * 128 + 2 * l + 1], a1);
      a0 = 0; a1 = 0; cur = g;
    }
    float2 f = unpack2h(y[(size_t)n * 64 + l]);
    a0 += fmaxf(f.x * A0 + B0, 0.f);
    a1 += fmaxf(f.y * A1 + B1, 0.f);
  }
  atomicAdd(&xg[(size_t)cur * 128 + 2 * l], a0);
  atomicAdd(&xg[(size_t)cur * 128 + 2 * l + 1], a1);
}

extern "C" void kernel_launch(void* const* d_in, const int* in_sizes, int n_in,
                              void* d_out, int out_size, void* d_ws, size_t ws_size,
                              hipStream_t stream) {
  const float* h    = (const float*)d_in[0];
  const int*   esrc = (const int*)d_in[1];
  const int*   edst = (const int*)d_in[2];
  const int*   gid  = (const int*)d_in[3];
  const float* W1   = (const float*)d_in[4];
  const float* b1   = (const float*)d_in[5];
  const float* g1g  = (const float*)d_in[6];
  const float* g1b  = (const float*)d_in[7];
  const float* Wg   = (const float*)d_in[8];
  const float* bg   = (const float*)d_in[9];
  const float* gg   = (const float*)d_in[10];
  const float* gb   = (const float*)d_in[11];
  const float* fc1W = (const float*)d_in[12];
  const float* fc1b = (const float*)d_in[13];
  const float* bn1g = (const float*)d_in[14];
  const float* bn1b = (const float*)d_in[15];
  const float* linW = (const float*)d_in[16];
  const float* linb = (const float*)d_in[17];
  const float* lbng = (const float*)d_in[18];
  const float* lbnb = (const float*)d_in[19];
  const float* fc2W = (const float*)d_in[20];
  const float* fc2b = (const float*)d_in[21];
  float* out = (float*)d_out;

  char* p = (char*)d_ws;
  auto alloc = [&](size_t bytes) {
    char* q = p;
    p += (bytes + 255) & ~(size_t)255;
    return q;
  };
  int* row_ptr = (int*)alloc((N_NODES + 1) * sizeof(int));
  int* bcnt    = (int*)alloc(NBUCK * sizeof(int));
  int* bbase   = (int*)alloc((NBUCK + 1) * sizeof(int));
  int* bcur    = (int*)alloc(NBUCK * sizeof(int));
  uint* csrb   = (uint*)alloc(N_EDGES * sizeof(uint));
  uint* hb     = (uint*)alloc((size_t)N_NODES * 64 * sizeof(uint));
  uint* Mb     = (uint*)alloc((size_t)N_NODES * 64 * sizeof(uint));
  uint* yb     = (uint*)alloc((size_t)N_NODES * 64 * sizeof(uint));
  ushort* Wt   = (ushort*)alloc(5 * 128 * 128 * sizeof(ushort));
  ushort* fc1Wt = (ushort*)alloc(512 * 128 * sizeof(ushort));
  ushort* linWt = (ushort*)alloc(256 * 512 * sizeof(ushort));
  ushort* fc2Wt = (ushort*)alloc(256 * 256 * sizeof(ushort));
  float* stats = (float*)alloc(2816 * sizeof(float));
  float* Ac    = (float*)alloc(512 * sizeof(float));
  float* Bc    = (float*)alloc(512 * sizeof(float));
  float* xg    = (float*)alloc((size_t)N_GRAPHS * 128 * sizeof(float));
  uint* y1b    = (uint*)alloc((size_t)N_GRAPHS * 256 * sizeof(uint));
  uint* y2b    = (uint*)alloc((size_t)N_GRAPHS * 128 * sizeof(uint));
  uint* staging = (uint*)Mb;  // 6.4 MB aliases Mb (dead until layer loop)

  float* lsum = stats;                 // [layer]*256
  float* fsum1 = stats + 1280;         // 512
  float* fsq1  = stats + 1792;         // 512
  float* lsum2 = stats + 2304;         // 256
  float* lsq2  = stats + 2560;         // 256

  // ---- prep: conversions + weights ----
  k_conv_h<<<(N_NODES * 64 + 255) / 256, 256, 0, stream>>>(h, hb, N_NODES);
  {
    dim3 g(64, 5);
    k_prep_wt_all<<<g, 256, 0, stream>>>(W1, Wg, Wt);
  }
  k_prep_wt_gen<<<(512 * 128 + 255) / 256, 256, 0, stream>>>(fc1W, 512, 0, 512, 128, fc1Wt, 512 * 128);
  k_prep_wt_gen<<<(256 * 512 + 255) / 256, 256, 0, stream>>>(linW, 256, 0, 256, 512, linWt, 256 * 512);
  k_prep_wt_gen<<<(256 * 256 + 255) / 256, 256, 0, stream>>>(fc2W, 408, 204, 204, 256, fc2Wt, 256 * 256);

  hipMemsetAsync(stats, 0, 2816 * sizeof(float), stream);
  hipMemsetAsync(xg, 0, (size_t)N_GRAPHS * 128 * sizeof(float), stream);

  // ---- CSR build ----
  hipMemsetAsync(bcnt, 0, NBUCK * sizeof(int), stream);
  k_bin_count<<<(N_EDGES + BIN_CHUNK - 1) / BIN_CHUNK, 256, 0, stream>>>(edst, bcnt, N_EDGES);
  k_bucket_scan<<<1, 512, 0, stream>>>(bcnt, bbase, bcur);
  k_bin<<<(N_EDGES + BIN_CHUNK - 1) / BIN_CHUNK, 256, 0, stream>>>(esrc, edst, bcur,
                                                                   staging, N_EDGES);
  k_place2<<<NBUCK, 256, 0, stream>>>(staging, bbase, row_ptr, csrb, N_NODES, N_EDGES);

  const float invN = 1.0f / (float)N_NODES;
  const float invG = 1.0f / (float)N_GRAPHS;

  // ---- 5 GIN layers: agg(+inline prev BN/ReLU) -> MFMA GEMM(+stats) ----
  for (int layer = 0; layer < 5; layer++) {
    const ushort* Wl = Wt + (size_t)layer * 128 * 128;
    const float* bl  = (layer == 0) ? b1 : bg + (size_t)(layer - 1) * 128;
    const float* pg  = (layer == 1) ? g1g : gg + (size_t)(layer - 2) * 128;
    const float* pb  = (layer == 1) ? g1b : gb + (size_t)(layer - 2) * 128;
    float* st = lsum + (size_t)layer * 256;

    if (layer == 0)
      k_agg_f<false><<<(N_NODES + 3) / 4, 256, 0, stream>>>(hb, row_ptr, csrb,
                                                            nullptr, nullptr, nullptr, nullptr,
                                                            invN, Mb, N_NODES);
    else
      k_agg_f<true><<<(N_NODES + 3) / 4, 256, 0, stream>>>(yb, row_ptr, csrb,
                                                           lsum + (size_t)(layer - 1) * 256,
                                                           lsum + (size_t)(layer - 1) * 256 + 128,
                                                           pg, pb, invN, Mb, N_NODES);
    k_gemm_mfma<<<(N_NODES + 127) / 128, 256, 0, stream>>>((const ushort*)Mb, Wl, bl, 2.0f,
                                                           (ushort*)yb, N_NODES,
                                                           st, st + 128);
  }

  // ---- readout (inline layer-5 BN+ReLU) ----
  k_readout<<<(N_NODES + 63) / 64, 64, 0, stream>>>(yb, gid,
                                                    lsum + 4 * 256, lsum + 4 * 256 + 128,
                                                    gg + 3 * 128, gb + 3 * 128, invN,
                                                    xg, N_NODES);

  // ---- fc1 (128 -> 512): fp32 A, fused stats ----
  k_head_mfma<0, 0><<<dim3(4, 16), 256, 0, stream>>>(xg, N_GRAPHS, 128, fc1Wt, fc1b, 0, 512,
                                                     nullptr, nullptr, y1b, 512, fsum1, fsq1);
  k_bnparams<<<1, 512, 0, stream>>>(fsum1, fsq1, bn1g, bn1b, Ac, Bc, 512, invG);

  // ---- lin (512 -> 256): fp16 A + inline bn1/relu, fused stats ----
  k_head_mfma<1, 0><<<dim3(2, 16), 256, 0, stream>>>(y1b, N_GRAPHS, 512, linWt, linb, 0, 256,
                                                     Ac, Bc, y2b, 256, lsum2, lsq2);
  k_bnparams<<<1, 256, 0, stream>>>(lsum2, lsq2, lbng, lbnb, Ac, Bc, 256, invG);

  // ---- fc2 (256 -> 204): fp16 A + inline lbn/relu, sigmoid, write out ----
  k_head_mfma<1, 1><<<dim3(2, 16), 256, 0, stream>>>(y2b, N_GRAPHS, 256, fc2Wt, fc2b, 204, NCLS,
                                                     Ac, Bc, out, NCLS, nullptr, nullptr);
}